// Round 4
// baseline (299.944 us; speedup 1.0000x reference)
//
#include <hip/hip_runtime.h>

typedef unsigned short u16;
typedef u16 ushort8 __attribute__((ext_vector_type(8)));
typedef __bf16 bf16x8 __attribute__((ext_vector_type(8)));
typedef float f32x4 __attribute__((ext_vector_type(4)));
typedef long long ll;

__device__ __forceinline__ u16 f2bf(float f) {
    unsigned u = __builtin_bit_cast(unsigned, f);
    u += 0x7FFFu + ((u >> 16) & 1u);
    return (u16)(u >> 16);
}

// async global->LDS, 16B per lane, wave-uniform LDS base + lane*16
#define GLOAD16(dst, src) \
    __builtin_amdgcn_global_load_lds( \
        (const __attribute__((address_space(1))) void*)(src), \
        (__attribute__((address_space(3))) void*)(dst), 16, 0, 0)

// ---------------------------------------------------------------------------
// Effective QKV weights, stacked+transposed: rows 0-511 q, 512-1023 k, 1024+ v
// ---------------------------------------------------------------------------
__global__ __launch_bounds__(256) void reduce_qkv_w(
    const float* __restrict__ Wq, const float* __restrict__ Wk,
    const float* __restrict__ Wv, u16* __restrict__ WqkvT)
{
    int idx = blockIdx.x * 256 + threadIdx.x;   // 0 .. 512*512-1
    int e = idx & 511, d = idx >> 9;
    float sq = 0.f, sk = 0.f, sv = 0.f;
#pragma unroll
    for (int h = 0; h < 8; ++h) {
        ll off = (ll)(h * 512 + d) * 512 + e;
        sq += Wq[off]; sk += Wk[off]; sv += Wv[off];
    }
    int o = e * 512 + d;
    WqkvT[o] = f2bf(sq);
    WqkvT[512 * 512 + o] = f2bf(sk);
    WqkvT[1024 * 512 + o] = f2bf(sv);
}

__global__ __launch_bounds__(256) void concat_bias(
    const float* __restrict__ bq, const float* __restrict__ bk,
    const float* __restrict__ bv, float* __restrict__ bqkv)
{
    int i = blockIdx.x * 256 + threadIdx.x;  // 0..1535
    float v = (i < 512) ? bq[i] : (i < 1024 ? bk[i - 512] : bv[i - 1024]);
    bqkv[i] = v;
}

// ---------------------------------------------------------------------------
__global__ __launch_bounds__(256) void cvt_f32_bf16(
    const float* __restrict__ in, u16* __restrict__ out, ll n)
{
    ll i = ((ll)blockIdx.x * 256 + threadIdx.x) * 8;
    if (i >= n) return;
    float4 a = *(const float4*)&in[i];
    float4 b = *(const float4*)&in[i + 4];
    ushort8 o;
    o[0] = f2bf(a.x); o[1] = f2bf(a.y); o[2] = f2bf(a.z); o[3] = f2bf(a.w);
    o[4] = f2bf(b.x); o[5] = f2bf(b.y); o[6] = f2bf(b.z); o[7] = f2bf(b.w);
    *(ushort8*)&out[i] = o;
}

// ---------------------------------------------------------------------------
// 64x64 LDS transpose: out[c][r] = bf16(in[r][c]); grid (R/64, C/64, batch)
// ---------------------------------------------------------------------------
template<bool SRC_F32>
__global__ __launch_bounds__(256) void transpose_k(
    const void* __restrict__ in, u16* __restrict__ out,
    int ldin, int ldout, ll inB, ll outB)
{
    __shared__ u16 tile[64][65];
    int b = blockIdx.z;
    int r0 = blockIdx.x * 64, c0 = blockIdx.y * 64;
#pragma unroll
    for (int i = 0; i < 16; ++i) {
        int lin = threadIdx.x + i * 256;
        int rr = lin >> 6, cc = lin & 63;
        ll src = (ll)b * inB + (ll)(r0 + rr) * ldin + (c0 + cc);
        u16 val = SRC_F32 ? f2bf(((const float*)in)[src]) : ((const u16*)in)[src];
        tile[rr][cc] = val;
    }
    __syncthreads();
#pragma unroll
    for (int i = 0; i < 16; ++i) {
        int lin = threadIdx.x + i * 256;
        int rr = lin >> 6, cc = lin & 63;
        out[(ll)b * outB + (ll)(c0 + rr) * ldout + (r0 + cc)] = tile[cc][rr];
    }
}

// ---------------------------------------------------------------------------
// bf16 MFMA GEMM with async LDS staging and optional split-K (round-3 proven)
// ---------------------------------------------------------------------------
template<bool OUT_BF16>
__global__ __launch_bounds__(256) void gemm2(
    const u16* __restrict__ A, const u16* __restrict__ Bt,
    void* __restrict__ C, const float* __restrict__ bias,
    int lda, int ldb, int ldc, int Kslice, int nsplit, float alpha,
    ll strideA, ll strideB, ll strideC, ll sliceStrideC)
{
    __shared__ __attribute__((aligned(16))) u16 smA[128 * 32];
    __shared__ __attribute__((aligned(16))) u16 smB[128 * 32];

    const int z = blockIdx.z;
    const int b = z / nsplit, s = z - b * nsplit;
    A  += (ll)b * strideA + (ll)s * Kslice;
    Bt += (ll)b * strideB + (ll)s * Kslice;
    const ll cbase = (ll)b * strideC + (ll)s * sliceStrideC;

    const int bm = blockIdx.x * 128, bn = blockIdx.y * 128;
    const int t = threadIdx.x, w = t >> 6, l = t & 63;
    const int wm = (w >> 1) * 64, wn = (w & 1) * 64;
    const int lr = l & 15, lg = l >> 4;

    const int r0 = w * 32 + (l >> 2);
    const int cs = (l & 3) * 8;
    const u16* ga0 = A + (ll)(bm + r0) * lda + cs;
    const u16* ga1 = A + (ll)(bm + r0 + 16) * lda + cs;
    const u16* gb0 = Bt + (ll)(bn + r0) * ldb + cs;
    const u16* gb1 = Bt + (ll)(bn + r0 + 16) * ldb + cs;
    u16* la0 = &smA[(w * 32) * 32];
    u16* la1 = &smA[(w * 32 + 16) * 32];
    u16* lb0 = &smB[(w * 32) * 32];
    u16* lb1 = &smB[(w * 32 + 16) * 32];

    f32x4 acc[4][4] = {};

    for (int k0 = 0; k0 < Kslice; k0 += 32) {
        GLOAD16(la0, ga0);
        GLOAD16(la1, ga1);
        GLOAD16(lb0, gb0);
        GLOAD16(lb1, gb1);
        ga0 += 32; ga1 += 32; gb0 += 32; gb1 += 32;
        __syncthreads();

        bf16x8 af[4], bfr[4];
#pragma unroll
        for (int i = 0; i < 4; ++i)
            af[i] = *(const bf16x8*)&smA[(wm + i * 16 + lr) * 32 + lg * 8];
#pragma unroll
        for (int i = 0; i < 4; ++i)
            bfr[i] = *(const bf16x8*)&smB[(wn + i * 16 + lr) * 32 + lg * 8];
#pragma unroll
        for (int mi = 0; mi < 4; ++mi)
#pragma unroll
            for (int ni = 0; ni < 4; ++ni)
                acc[mi][ni] = __builtin_amdgcn_mfma_f32_16x16x32_bf16(
                    af[mi], bfr[ni], acc[mi][ni], 0, 0, 0);
        __syncthreads();
    }

    const bool addb = (bias != nullptr) && (s == 0);
#pragma unroll
    for (int ni = 0; ni < 4; ++ni) {
        const int col = bn + wn + ni * 16 + lr;
        const float bv = addb ? bias[col] : 0.f;
#pragma unroll
        for (int mi = 0; mi < 4; ++mi) {
#pragma unroll
            for (int j = 0; j < 4; ++j) {
                const int row = bm + wm + mi * 16 + lg * 4 + j;
                const ll off = cbase + (ll)row * ldc + col;
                const float v = acc[mi][ni][j] * alpha + bv;
                if (OUT_BF16) ((u16*)C)[off] = f2bf(v);
                else          ((float*)C)[off] = v;
            }
        }
    }
}

// ---------------------------------------------------------------------------
// Fused flash attention: y[b][q][d] = softmax(q@k^T/8) @ v, D=512, S=2048.
// Block: 256 thr / 4 waves, 16 Q-rows, 32 keys/iter, 64 iters.
// Wave w owns D-range [w*128, (w+1)*128) for both QK^T partial and PV.
// grid: (S/16, 1, B)
// ---------------------------------------------------------------------------
__global__ __launch_bounds__(256) void fattn(
    const u16* __restrict__ qkv,   // [B*S][1536] q|k|v (bias included)
    const u16* __restrict__ vT,    // [B][512][S] bf16
    float* __restrict__ y)         // [B*S][512]
{
    // Kt[key][512d], row = 1KB = 64 chunks of 16B, chunk swizzled ^ (key&7)
    // Vt[d][32key],  row = 64B = 4 chunks of 16B, chunk swizzled ^ ((d>>1)&3)
    __shared__ __attribute__((aligned(16))) u16 Kt[32 * 512];
    __shared__ __attribute__((aligned(16))) u16 Vt[512 * 32];
    __shared__ __attribute__((aligned(16))) float Sp[4][16][33];

    const int b = blockIdx.z;
    const int q0 = blockIdx.x * 16;
    const int t = threadIdx.x;
    const int w = t >> 6, l = t & 63;
    const int lr = l & 15, lg = l >> 4;

    // Q A-frags for this wave's D-range (row = lr, k contiguous at lg*8)
    const ll rowQ = (ll)(b * 2048 + q0 + lr) * 1536;
    bf16x8 qf[4];
#pragma unroll
    for (int ks = 0; ks < 4; ++ks)
        qf[ks] = *(const bf16x8*)&qkv[rowQ + w * 128 + ks * 32 + lg * 8];

    // staging sources (pre-swizzled per-lane global addresses, G21 pattern)
    const u16* ksrc[8];
    const u16* vsrc[8];
#pragma unroll
    for (int g = 0; g < 8; ++g) {
        // K rows w*8+g; (w*8+g)&7 == g; lane covers LDS chunk l, global chunk l^g
        ksrc[g] = qkv + ((ll)(b * 2048 + w * 8 + g) * 1536 + 512) + (ll)((l ^ g) * 8);
        // V dcols d0+(l>>2); lane LDS chunk l&3, global chunk (l&3)^((d>>1)&3)
        int d = w * 128 + g * 16 + (l >> 2);
        vsrc[g] = vT + ((ll)b * 512 + d) * 2048 + (ll)((((l & 3) ^ ((d >> 1) & 3))) * 8);
    }

    f32x4 acc[8] = {};
    float m_run = -1e30f, l_run = 0.f;

    for (int it = 0; it < 64; ++it) {
        __syncthreads();   // previous iter's LDS reads done
#pragma unroll
        for (int g = 0; g < 8; ++g)
            GLOAD16(&Kt[(w * 8 + g) * 512], ksrc[g]);
#pragma unroll
        for (int g = 0; g < 8; ++g)
            GLOAD16(&Vt[(w * 128 + g * 16) * 32], vsrc[g]);
#pragma unroll
        for (int g = 0; g < 8; ++g) { ksrc[g] += 32 * 1536; vsrc[g] += 32; }
        __syncthreads();   // drains vmcnt -> tiles ready

        // QK^T partial over D-range: S_w[16 qrow][32 key]
        f32x4 sacc[2] = {};
#pragma unroll
        for (int ni = 0; ni < 2; ++ni) {
            const int kr = ni * 16 + lr;
#pragma unroll
            for (int ks = 0; ks < 4; ++ks) {
                int ch = ((w * 4 + ks) * 4 + lg) ^ (kr & 7);
                bf16x8 kf = *(const bf16x8*)&Kt[kr * 512 + ch * 8];
                sacc[ni] = __builtin_amdgcn_mfma_f32_16x16x32_bf16(
                    qf[ks], kf, sacc[ni], 0, 0, 0);
            }
        }
        // C-layout: col(=key within frag) = lr, row(=qrow) = lg*4+j
#pragma unroll
        for (int ni = 0; ni < 2; ++ni)
#pragma unroll
            for (int j = 0; j < 4; ++j)
                Sp[w][lg * 4 + j][ni * 16 + lr] = sacc[ni][j];
        __syncthreads();   // Sp complete

        // combine partials; lane owns qrow = lr, keys lg*8 .. lg*8+7
        float s[8];
#pragma unroll
        for (int i = 0; i < 8; ++i) {
            int key = lg * 8 + i;
            s[i] = 0.125f * (Sp[0][lr][key] + Sp[1][lr][key] +
                             Sp[2][lr][key] + Sp[3][lr][key]);
        }
        // online softmax (per qrow, replicated across lg groups)
        float mt = s[0];
#pragma unroll
        for (int i = 1; i < 8; ++i) mt = fmaxf(mt, s[i]);
        mt = fmaxf(mt, __shfl_xor(mt, 16));
        mt = fmaxf(mt, __shfl_xor(mt, 32));
        float mnew = fmaxf(m_run, mt);
        float fac = __expf(m_run - mnew);
        float p[8], lt = 0.f;
#pragma unroll
        for (int i = 0; i < 8; ++i) { p[i] = __expf(s[i] - mnew); lt += p[i]; }
        lt += __shfl_xor(lt, 16);
        lt += __shfl_xor(lt, 32);
        l_run = l_run * fac + lt;
        m_run = mnew;
        // rescale O acc (acc rows are qrow = lg*4+j; fac lives at lane qrow)
#pragma unroll
        for (int j = 0; j < 4; ++j) {
            float fj = __shfl(fac, lg * 4 + j);
#pragma unroll
            for (int ni = 0; ni < 8; ++ni) acc[ni][j] *= fj;
        }
        // P -> bf16; already in A-frag layout (row=lr, keys lg*8..)
        ushort8 pu;
#pragma unroll
        for (int i = 0; i < 8; ++i) pu[i] = f2bf(p[i]);
        bf16x8 pb = __builtin_bit_cast(bf16x8, pu);
        // PV: O[16 qrow][128 dcol] += P @ V
#pragma unroll
        for (int ni = 0; ni < 8; ++ni) {
            int d = w * 128 + ni * 16 + lr;
            int ch = lg ^ ((d >> 1) & 3);
            bf16x8 vf = *(const bf16x8*)&Vt[d * 32 + ch * 8];
            acc[ni] = __builtin_amdgcn_mfma_f32_16x16x32_bf16(pb, vf, acc[ni], 0, 0, 0);
        }
    }

    // epilogue: O /= l, write fp32
    float linv = 1.f / l_run;
#pragma unroll
    for (int j = 0; j < 4; ++j) {
        float lj = __shfl(linv, lg * 4 + j);
        ll row = (ll)(b * 2048 + q0 + lg * 4 + j);
#pragma unroll
        for (int ni = 0; ni < 8; ++ni)
            y[row * 512 + w * 128 + ni * 16 + lr] = acc[ni][j] * lj;
    }
}

// ---------------------------------------------------------------------------
// out = LayerNorm(a + b [+ c]) * gamma + beta over rows of 512 (1 wave/row)
// ---------------------------------------------------------------------------
__global__ __launch_bounds__(64) void add_ln3(
    const float* __restrict__ a, const float* __restrict__ b,
    const float* __restrict__ c,
    const float* __restrict__ gamma, const float* __restrict__ beta,
    float* __restrict__ outf, u16* __restrict__ outb)
{
    ll row = blockIdx.x;
    const float* pa = a + row * 512;
    const float* pb = b + row * 512;
    int l = threadIdx.x;
    float4 a0 = *(const float4*)&pa[l * 8], a1 = *(const float4*)&pa[l * 8 + 4];
    float4 b0 = *(const float4*)&pb[l * 8], b1 = *(const float4*)&pb[l * 8 + 4];
    float x[8] = { a0.x + b0.x, a0.y + b0.y, a0.z + b0.z, a0.w + b0.w,
                   a1.x + b1.x, a1.y + b1.y, a1.z + b1.z, a1.w + b1.w };
    if (c) {
        const float* pc = c + row * 512;
        float4 c0 = *(const float4*)&pc[l * 8], c1 = *(const float4*)&pc[l * 8 + 4];
        x[0] += c0.x; x[1] += c0.y; x[2] += c0.z; x[3] += c0.w;
        x[4] += c1.x; x[5] += c1.y; x[6] += c1.z; x[7] += c1.w;
    }
    float s = 0.f, ss = 0.f;
#pragma unroll
    for (int i = 0; i < 8; ++i) { s += x[i]; ss += x[i] * x[i]; }
#pragma unroll
    for (int off = 32; off; off >>= 1) {
        s += __shfl_xor(s, off);
        ss += __shfl_xor(ss, off);
    }
    float mean = s * (1.f / 512.f);
    float var = ss * (1.f / 512.f) - mean * mean;
    float rs = rsqrtf(var + 1e-14f);
    float o[8];
#pragma unroll
    for (int i = 0; i < 8; ++i)
        o[i] = (x[i] - mean) * rs * gamma[l * 8 + i] + beta[l * 8 + i];
    if (outf) {
        float4 o0 = { o[0], o[1], o[2], o[3] }, o1 = { o[4], o[5], o[6], o[7] };
        *(float4*)&outf[row * 512 + l * 8] = o0;
        *(float4*)&outf[row * 512 + l * 8 + 4] = o1;
    }
    if (outb) {
        ushort8 ob;
#pragma unroll
        for (int i = 0; i < 8; ++i) ob[i] = f2bf(o[i]);
        *(ushort8*)&outb[row * 512 + l * 8] = ob;
    }
}

// ---------------------------------------------------------------------------
extern "C" void kernel_launch(void* const* d_in, const int* in_sizes, int n_in,
                              void* d_out, int out_size, void* d_ws, size_t ws_size,
                              hipStream_t stream)
{
    const float* x      = (const float*)d_in[0];
    const float* Wq     = (const float*)d_in[1];
    const float* bq     = (const float*)d_in[2];
    const float* Wk     = (const float*)d_in[3];
    const float* bk     = (const float*)d_in[4];
    const float* Wv     = (const float*)d_in[5];
    const float* bv     = (const float*)d_in[6];
    const float* gamma1 = (const float*)d_in[7];
    const float* beta1  = (const float*)d_in[8];
    const float* gamma2 = (const float*)d_in[9];
    const float* beta2  = (const float*)d_in[10];
    const float* W1     = (const float*)d_in[11];
    const float* b1     = (const float*)d_in[12];
    const float* W2     = (const float*)d_in[13];
    const float* b2     = (const float*)d_in[14];

    const int B = 4, S = 2048, D = 512, F = 2048;
    const int BS = B * S;  // 8192

    char* w = (char*)d_ws;
    auto alloc = [&](size_t bytes) {
        char* p = w;
        w += (bytes + 255) & ~(size_t)255;
        return p;
    };
    u16* wqkvT = (u16*)alloc((size_t)3 * D * D * 2);   // [1536][512]
    float* bqkv = (float*)alloc((size_t)3 * D * 4);
    u16* w1T = (u16*)alloc((size_t)F * D * 2);         // [F][D]
    u16* w2T = (u16*)alloc((size_t)D * F * 2);         // [D][F]
    u16* xb  = (u16*)alloc((size_t)BS * D * 2);        // reused as hb
    u16* qkvb = (u16*)alloc((size_t)BS * 3 * D * 2);   // [BS][1536]
    u16* vT  = (u16*)alloc((size_t)B * D * S * 2);     // [B][512][2048]
    float* y = (float*)alloc((size_t)BS * D * 4);      // reused as f0
    float* h = (float*)alloc((size_t)BS * D * 4);
    u16* f1  = (u16*)alloc((size_t)BS * F * 2);        // [BS][F] bf16
    float* f1p = (float*)alloc((size_t)BS * D * 4);    // FFN2 partial 1
    u16* hb = xb;
    float* f0 = y;                                     // FFN2 partial 0 (y dead)

    // 1. effective QKV weights (stacked/transposed) + bias concat
    reduce_qkv_w<<<dim3(D * D / 256), 256, 0, stream>>>(Wq, Wk, Wv, wqkvT);
    concat_bias<<<dim3(6), 256, 0, stream>>>(bq, bk, bv, bqkv);
    // 2-3. W1T [F][D], W2T [D][F]
    transpose_k<true><<<dim3(D / 64, F / 64, 1), 256, 0, stream>>>(
        W1, w1T, F, D, 0, 0);
    transpose_k<true><<<dim3(F / 64, D / 64, 1), 256, 0, stream>>>(
        W2, w2T, D, F, 0, 0);
    // 4. x -> bf16
    cvt_f32_bf16<<<dim3(BS * D / 8 / 256), 256, 0, stream>>>(x, xb, (ll)BS * D);
    // 5. fused qkv = x @ Wqkv^T + bqkv -> [BS][1536]
    gemm2<true><<<dim3(BS / 128, 3 * D / 128, 1), 256, 0, stream>>>(
        xb, wqkvT, qkvb, bqkv, D, D, 3 * D, D, 1, 1.f, 0, 0, 0, 0);
    // 6. vT[b][e][t] = v[b][t][e]
    transpose_k<false><<<dim3(S / 64, D / 64, B), 256, 0, stream>>>(
        qkvb + 2 * D, vT, 3 * D, S, (ll)S * 3 * D, (ll)D * S);
    // 7. fused flash attention -> y fp32
    fattn<<<dim3(S / 16, 1, B), 256, 0, stream>>>(qkvb, vT, y);
    // 8. h = LN(x + y) -> fp32 + bf16
    add_ln3<<<dim3(BS), 64, 0, stream>>>(x, y, nullptr, gamma1, beta1, h, hb);
    // 9. f1 = h @ W1 + b1 (bf16)
    gemm2<true><<<dim3(BS / 128, F / 128, 1), 256, 0, stream>>>(
        hb, w1T, f1, b1, D, D, F, D, 1, 1.f, 0, 0, 0, 0);
    // 10. f2 = f1 @ W2 + b2, split-K=2 -> fp32 partials f0, f1p (y dead)
    gemm2<false><<<dim3(BS / 128, D / 128, 2), 256, 0, stream>>>(
        f1, w2T, f0, b2, F, F, D, F / 2, 2, 1.f, 0, 0, 0,
        (ll)((f1p - f0)));
    // 11. out = LN(h + f0 + f1p)
    add_ln3<<<dim3(BS), 64, 0, stream>>>(h, f0, f1p, gamma2, beta2,
                                         (float*)d_out, nullptr);
}

// Round 5
// 238.888 us; speedup vs baseline: 1.2556x; 1.2556x over previous
//
#include <hip/hip_runtime.h>

typedef unsigned short u16;
typedef u16 ushort8 __attribute__((ext_vector_type(8)));
typedef __bf16 bf16x8 __attribute__((ext_vector_type(8)));
typedef float f32x4 __attribute__((ext_vector_type(4)));
typedef long long ll;

__device__ __forceinline__ u16 f2bf(float f) {
    unsigned u = __builtin_bit_cast(unsigned, f);
    u += 0x7FFFu + ((u >> 16) & 1u);
    return (u16)(u >> 16);
}

// async global->LDS, 16B per lane, wave-uniform LDS base + lane*16
#define GLOAD16(dst, src) \
    __builtin_amdgcn_global_load_lds( \
        (const __attribute__((address_space(1))) void*)(src), \
        (__attribute__((address_space(3))) void*)(dst), 16, 0, 0)

// ---------------------------------------------------------------------------
// Effective QKV weights, stacked+transposed: rows 0-511 q, 512-1023 k, 1024+ v
// ---------------------------------------------------------------------------
__global__ __launch_bounds__(256) void reduce_qkv_w(
    const float* __restrict__ Wq, const float* __restrict__ Wk,
    const float* __restrict__ Wv, u16* __restrict__ WqkvT)
{
    int idx = blockIdx.x * 256 + threadIdx.x;   // 0 .. 512*512-1
    int e = idx & 511, d = idx >> 9;
    float sq = 0.f, sk = 0.f, sv = 0.f;
#pragma unroll
    for (int h = 0; h < 8; ++h) {
        ll off = (ll)(h * 512 + d) * 512 + e;
        sq += Wq[off]; sk += Wk[off]; sv += Wv[off];
    }
    int o = e * 512 + d;
    WqkvT[o] = f2bf(sq);
    WqkvT[512 * 512 + o] = f2bf(sk);
    WqkvT[1024 * 512 + o] = f2bf(sv);
}

__global__ __launch_bounds__(256) void concat_bias(
    const float* __restrict__ bq, const float* __restrict__ bk,
    const float* __restrict__ bv, float* __restrict__ bqkv)
{
    int i = blockIdx.x * 256 + threadIdx.x;  // 0..1535
    float v = (i < 512) ? bq[i] : (i < 1024 ? bk[i - 512] : bv[i - 1024]);
    bqkv[i] = v;
}

// ---------------------------------------------------------------------------
__global__ __launch_bounds__(256) void cvt_f32_bf16(
    const float* __restrict__ in, u16* __restrict__ out, ll n)
{
    ll i = ((ll)blockIdx.x * 256 + threadIdx.x) * 8;
    if (i >= n) return;
    float4 a = *(const float4*)&in[i];
    float4 b = *(const float4*)&in[i + 4];
    ushort8 o;
    o[0] = f2bf(a.x); o[1] = f2bf(a.y); o[2] = f2bf(a.z); o[3] = f2bf(a.w);
    o[4] = f2bf(b.x); o[5] = f2bf(b.y); o[6] = f2bf(b.z); o[7] = f2bf(b.w);
    *(ushort8*)&out[i] = o;
}

// ---------------------------------------------------------------------------
// 64x64 LDS transpose: out[c][r] = bf16(in[r][c]); grid (R/64, C/64, batch)
// ---------------------------------------------------------------------------
template<bool SRC_F32>
__global__ __launch_bounds__(256) void transpose_k(
    const void* __restrict__ in, u16* __restrict__ out,
    int ldin, int ldout, ll inB, ll outB)
{
    __shared__ u16 tile[64][65];
    int b = blockIdx.z;
    int r0 = blockIdx.x * 64, c0 = blockIdx.y * 64;
#pragma unroll
    for (int i = 0; i < 16; ++i) {
        int lin = threadIdx.x + i * 256;
        int rr = lin >> 6, cc = lin & 63;
        ll src = (ll)b * inB + (ll)(r0 + rr) * ldin + (c0 + cc);
        u16 val = SRC_F32 ? f2bf(((const float*)in)[src]) : ((const u16*)in)[src];
        tile[rr][cc] = val;
    }
    __syncthreads();
#pragma unroll
    for (int i = 0; i < 16; ++i) {
        int lin = threadIdx.x + i * 256;
        int rr = lin >> 6, cc = lin & 63;
        out[(ll)b * outB + (ll)(c0 + rr) * ldout + (r0 + cc)] = tile[cc][rr];
    }
}

// ---------------------------------------------------------------------------
// bf16 MFMA GEMM with async LDS staging and optional split-K (proven)
// ---------------------------------------------------------------------------
template<bool OUT_BF16>
__global__ __launch_bounds__(256) void gemm2(
    const u16* __restrict__ A, const u16* __restrict__ Bt,
    void* __restrict__ C, const float* __restrict__ bias,
    int lda, int ldb, int ldc, int Kslice, int nsplit, float alpha,
    ll strideA, ll strideB, ll strideC, ll sliceStrideC)
{
    __shared__ __attribute__((aligned(16))) u16 smA[128 * 32];
    __shared__ __attribute__((aligned(16))) u16 smB[128 * 32];

    const int z = blockIdx.z;
    const int b = z / nsplit, s = z - b * nsplit;
    A  += (ll)b * strideA + (ll)s * Kslice;
    Bt += (ll)b * strideB + (ll)s * Kslice;
    const ll cbase = (ll)b * strideC + (ll)s * sliceStrideC;

    const int bm = blockIdx.x * 128, bn = blockIdx.y * 128;
    const int t = threadIdx.x, w = t >> 6, l = t & 63;
    const int wm = (w >> 1) * 64, wn = (w & 1) * 64;
    const int lr = l & 15, lg = l >> 4;

    const int r0 = w * 32 + (l >> 2);
    const int cs = (l & 3) * 8;
    const u16* ga0 = A + (ll)(bm + r0) * lda + cs;
    const u16* ga1 = A + (ll)(bm + r0 + 16) * lda + cs;
    const u16* gb0 = Bt + (ll)(bn + r0) * ldb + cs;
    const u16* gb1 = Bt + (ll)(bn + r0 + 16) * ldb + cs;
    u16* la0 = &smA[(w * 32) * 32];
    u16* la1 = &smA[(w * 32 + 16) * 32];
    u16* lb0 = &smB[(w * 32) * 32];
    u16* lb1 = &smB[(w * 32 + 16) * 32];

    f32x4 acc[4][4] = {};

    for (int k0 = 0; k0 < Kslice; k0 += 32) {
        GLOAD16(la0, ga0);
        GLOAD16(la1, ga1);
        GLOAD16(lb0, gb0);
        GLOAD16(lb1, gb1);
        ga0 += 32; ga1 += 32; gb0 += 32; gb1 += 32;
        __syncthreads();

        bf16x8 af[4], bfr[4];
#pragma unroll
        for (int i = 0; i < 4; ++i)
            af[i] = *(const bf16x8*)&smA[(wm + i * 16 + lr) * 32 + lg * 8];
#pragma unroll
        for (int i = 0; i < 4; ++i)
            bfr[i] = *(const bf16x8*)&smB[(wn + i * 16 + lr) * 32 + lg * 8];
#pragma unroll
        for (int mi = 0; mi < 4; ++mi)
#pragma unroll
            for (int ni = 0; ni < 4; ++ni)
                acc[mi][ni] = __builtin_amdgcn_mfma_f32_16x16x32_bf16(
                    af[mi], bfr[ni], acc[mi][ni], 0, 0, 0);
        __syncthreads();
    }

    const bool addb = (bias != nullptr) && (s == 0);
#pragma unroll
    for (int ni = 0; ni < 4; ++ni) {
        const int col = bn + wn + ni * 16 + lr;
        const float bv = addb ? bias[col] : 0.f;
#pragma unroll
        for (int mi = 0; mi < 4; ++mi) {
#pragma unroll
            for (int j = 0; j < 4; ++j) {
                const int row = bm + wm + mi * 16 + lg * 4 + j;
                const ll off = cbase + (ll)row * ldc + col;
                const float v = acc[mi][ni][j] * alpha + bv;
                if (OUT_BF16) ((u16*)C)[off] = f2bf(v);
                else          ((float*)C)[off] = v;
            }
        }
    }
}

// ---------------------------------------------------------------------------
// Fused flash attention v2. QBLK=32 q-rows/block, KVBLK=32, split-KV x2.
// 4 waves = (q-half qh) x (D-half dh). Wave: Q[16 rows][256 d] in regs,
// O acc [16 rows][256 d] fp32. Emits UNNORMALIZED O partial + (m,l) per row.
// grid: (S/32, 2, B)
// ---------------------------------------------------------------------------
__global__ __launch_bounds__(256) void fattn2(
    const u16* __restrict__ qkv,   // [B*S][1536] q|k|v (bias included)
    const u16* __restrict__ vT,    // [B][512][2048]
    float* __restrict__ Op,        // [2][B*S][512] unnormalized partials
    float* __restrict__ mArr,      // [2][B*S]
    float* __restrict__ lArr)      // [2][B*S]
{
    // Kt[key][512d]: row 1KB; LDS chunk c of row r holds global chunk c^(r&7)
    // Vt[d][32key]:  row 64B;  LDS chunk c of row d holds global chunk c^((d>>1)&3)
    __shared__ __attribute__((aligned(16))) u16 Kt[32 * 512];      // 32 KB
    __shared__ __attribute__((aligned(16))) u16 Vt[512 * 32];      // 32 KB
    __shared__ __attribute__((aligned(16))) float Sp[2][2][16][32]; // 8 KB

    const int b = blockIdx.z;
    const int kvs = blockIdx.y;
    const int q0 = blockIdx.x * 32;
    const int t = threadIdx.x;
    const int w = t >> 6, l = t & 63;
    const int qh = w >> 1, dh = w & 1;
    const int lr = l & 15, lg = l >> 4;

    // Q A-frags: rows q0+qh*16+lr, d = dh*256 + ks*32 + lg*8
    const ll rowQ = (ll)(b * 2048 + q0 + qh * 16 + lr) * 1536;
    bf16x8 qf[8];
#pragma unroll
    for (int ks = 0; ks < 8; ++ks)
        qf[ks] = *(const bf16x8*)&qkv[rowQ + dh * 256 + ks * 32 + lg * 8];

    // staging sources (pre-swizzled per-lane global addresses)
    const int key0 = kvs * 1024;
    const u16* ksrc[8];
    const u16* vsrc[8];
#pragma unroll
    for (int g = 0; g < 8; ++g) {
        // K rows w*8+g (r&7 == g); lane LDS chunk l <- global chunk l^g
        ksrc[g] = qkv + ((ll)(b * 2048 + key0 + w * 8 + g) * 1536 + 512)
                      + (ll)((l ^ g) * 8);
        // V d-rows w*128+g*16+(l>>2); lane LDS chunk l&3 <- global (l&3)^((d>>1)&3)
        int d = w * 128 + g * 16 + (l >> 2);
        vsrc[g] = vT + ((ll)b * 512 + d) * 2048 + key0
                     + (ll)((((l & 3) ^ ((d >> 1) & 3))) * 8);
    }

    f32x4 acc[16] = {};
    float m_run = -1e30f, l_run = 0.f;

    for (int it = 0; it < 32; ++it) {
        __syncthreads();   // all LDS reads of previous iter done
#pragma unroll
        for (int g = 0; g < 8; ++g)
            GLOAD16(&Kt[(w * 8 + g) * 512], ksrc[g]);
#pragma unroll
        for (int g = 0; g < 8; ++g)
            GLOAD16(&Vt[(w * 128 + g * 16) * 32], vsrc[g]);
#pragma unroll
        for (int g = 0; g < 8; ++g) { ksrc[g] += 32 * 1536; vsrc[g] += 32; }
        __syncthreads();   // staging complete (barrier drains vmcnt)

        // QK^T partial over this wave's 256-d half: S[16 q][32 key]
        f32x4 sacc[2] = {};
#pragma unroll
        for (int ni = 0; ni < 2; ++ni) {
            const int kr = ni * 16 + lr;
#pragma unroll
            for (int ks = 0; ks < 8; ++ks) {
                int ch = (dh * 32 + ks * 4 + lg) ^ (kr & 7);
                bf16x8 kf = *(const bf16x8*)&Kt[kr * 512 + ch * 8];
                sacc[ni] = __builtin_amdgcn_mfma_f32_16x16x32_bf16(
                    qf[ks], kf, sacc[ni], 0, 0, 0);
            }
        }
        // C-layout: col(key) = lr, row(q) = lg*4+j
#pragma unroll
        for (int ni = 0; ni < 2; ++ni)
#pragma unroll
            for (int j = 0; j < 4; ++j)
                Sp[qh][dh][lg * 4 + j][ni * 16 + lr] = sacc[ni][j];
        __syncthreads();   // Sp visible

        // combine 2 D-halves; lane owns qrow lr, keys lg*8..+8 (vector reads)
        float4 a0 = *(const float4*)&Sp[qh][0][lr][lg * 8];
        float4 a1 = *(const float4*)&Sp[qh][0][lr][lg * 8 + 4];
        float4 b0 = *(const float4*)&Sp[qh][1][lr][lg * 8];
        float4 b1 = *(const float4*)&Sp[qh][1][lr][lg * 8 + 4];
        float s[8] = { 0.125f * (a0.x + b0.x), 0.125f * (a0.y + b0.y),
                       0.125f * (a0.z + b0.z), 0.125f * (a0.w + b0.w),
                       0.125f * (a1.x + b1.x), 0.125f * (a1.y + b1.y),
                       0.125f * (a1.z + b1.z), 0.125f * (a1.w + b1.w) };
        // online softmax (replicated across lg groups; identical per qrow)
        float mt = s[0];
#pragma unroll
        for (int i = 1; i < 8; ++i) mt = fmaxf(mt, s[i]);
        mt = fmaxf(mt, __shfl_xor(mt, 16));
        mt = fmaxf(mt, __shfl_xor(mt, 32));
        float mnew = fmaxf(m_run, mt);
        float fac = __expf(m_run - mnew);
        float p[8], lt = 0.f;
#pragma unroll
        for (int i = 0; i < 8; ++i) { p[i] = __expf(s[i] - mnew); lt += p[i]; }
        lt += __shfl_xor(lt, 16);
        lt += __shfl_xor(lt, 32);
        l_run = l_run * fac + lt;
        m_run = mnew;
        // rescale O (acc rows are qrow = lg*4+j; fac lives at lane qrow)
#pragma unroll
        for (int j = 0; j < 4; ++j) {
            float fj = __shfl(fac, lg * 4 + j);
#pragma unroll
            for (int ni = 0; ni < 16; ++ni) acc[ni][j] *= fj;
        }
        // P -> bf16 A-frag (row=lr, keys lg*8..)
        ushort8 pu;
#pragma unroll
        for (int i = 0; i < 8; ++i) pu[i] = f2bf(p[i]);
        bf16x8 pb = __builtin_bit_cast(bf16x8, pu);
        // PV: O[16 q][256 d-half] += P @ V
#pragma unroll
        for (int ni = 0; ni < 16; ++ni) {
            int d = dh * 256 + ni * 16 + lr;
            int ch = lg ^ ((d >> 1) & 3);
            bf16x8 vf = *(const bf16x8*)&Vt[d * 32 + ch * 8];
            acc[ni] = __builtin_amdgcn_mfma_f32_16x16x32_bf16(pb, vf, acc[ni], 0, 0, 0);
        }
    }

    // write unnormalized partial O and per-row (m, l)
    float* Ob = Op + (ll)kvs * 8192 * 512;
#pragma unroll
    for (int j = 0; j < 4; ++j) {
        ll row = (ll)(b * 2048 + q0 + qh * 16 + lg * 4 + j);
#pragma unroll
        for (int ni = 0; ni < 16; ++ni)
            Ob[row * 512 + dh * 256 + ni * 16 + lr] = acc[ni][j];
    }
    if (dh == 0 && lg == 0) {
        int row = b * 2048 + q0 + qh * 16 + lr;
        mArr[kvs * 8192 + row] = m_run;
        lArr[kvs * 8192 + row] = l_run;
    }
}

// ---------------------------------------------------------------------------
// h = LayerNorm(x + merge(O0,O1,m,l)) : fused split-KV merge + add + LN
// 1 wave per row of 512.
// ---------------------------------------------------------------------------
__global__ __launch_bounds__(64) void add_ln_merge(
    const float* __restrict__ x, const float* __restrict__ Op,
    const float* __restrict__ mArr, const float* __restrict__ lArr,
    const float* __restrict__ gamma, const float* __restrict__ beta,
    float* __restrict__ outf, u16* __restrict__ outb)
{
    ll row = blockIdx.x;
    int l = threadIdx.x;
    float m0 = mArr[row], m1 = mArr[8192 + row];
    float l0 = lArr[row], l1 = lArr[8192 + row];
    float m = fmaxf(m0, m1);
    float c0 = __expf(m0 - m), c1 = __expf(m1 - m);
    float inv = 1.f / (c0 * l0 + c1 * l1);
    c0 *= inv; c1 *= inv;

    const float* px = x + row * 512;
    const float* p0 = Op + row * 512;
    const float* p1 = Op + (ll)8192 * 512 + row * 512;
    float4 x0 = *(const float4*)&px[l * 8], x1 = *(const float4*)&px[l * 8 + 4];
    float4 o00 = *(const float4*)&p0[l * 8], o01 = *(const float4*)&p0[l * 8 + 4];
    float4 o10 = *(const float4*)&p1[l * 8], o11 = *(const float4*)&p1[l * 8 + 4];
    float xv[8] = {
        x0.x + c0 * o00.x + c1 * o10.x, x0.y + c0 * o00.y + c1 * o10.y,
        x0.z + c0 * o00.z + c1 * o10.z, x0.w + c0 * o00.w + c1 * o10.w,
        x1.x + c0 * o01.x + c1 * o11.x, x1.y + c0 * o01.y + c1 * o11.y,
        x1.z + c0 * o01.z + c1 * o11.z, x1.w + c0 * o01.w + c1 * o11.w };
    float s = 0.f, ss = 0.f;
#pragma unroll
    for (int i = 0; i < 8; ++i) { s += xv[i]; ss += xv[i] * xv[i]; }
#pragma unroll
    for (int off = 32; off; off >>= 1) {
        s += __shfl_xor(s, off);
        ss += __shfl_xor(ss, off);
    }
    float mean = s * (1.f / 512.f);
    float var = ss * (1.f / 512.f) - mean * mean;
    float rs = rsqrtf(var + 1e-14f);
    float o[8];
#pragma unroll
    for (int i = 0; i < 8; ++i)
        o[i] = (xv[i] - mean) * rs * gamma[l * 8 + i] + beta[l * 8 + i];
    float4 of0 = { o[0], o[1], o[2], o[3] }, of1 = { o[4], o[5], o[6], o[7] };
    *(float4*)&outf[row * 512 + l * 8] = of0;
    *(float4*)&outf[row * 512 + l * 8 + 4] = of1;
    ushort8 ob;
#pragma unroll
    for (int i = 0; i < 8; ++i) ob[i] = f2bf(o[i]);
    *(ushort8*)&outb[row * 512 + l * 8] = ob;
}

// ---------------------------------------------------------------------------
// out = LayerNorm(a + b + c) * gamma + beta over rows of 512 (1 wave/row)
// ---------------------------------------------------------------------------
__global__ __launch_bounds__(64) void add_ln3(
    const float* __restrict__ a, const float* __restrict__ b,
    const float* __restrict__ c,
    const float* __restrict__ gamma, const float* __restrict__ beta,
    float* __restrict__ outf)
{
    ll row = blockIdx.x;
    const float* pa = a + row * 512;
    const float* pb = b + row * 512;
    const float* pc = c + row * 512;
    int l = threadIdx.x;
    float4 a0 = *(const float4*)&pa[l * 8], a1 = *(const float4*)&pa[l * 8 + 4];
    float4 b0 = *(const float4*)&pb[l * 8], b1 = *(const float4*)&pb[l * 8 + 4];
    float4 c0 = *(const float4*)&pc[l * 8], c1 = *(const float4*)&pc[l * 8 + 4];
    float xv[8] = { a0.x + b0.x + c0.x, a0.y + b0.y + c0.y,
                    a0.z + b0.z + c0.z, a0.w + b0.w + c0.w,
                    a1.x + b1.x + c1.x, a1.y + b1.y + c1.y,
                    a1.z + b1.z + c1.z, a1.w + b1.w + c1.w };
    float s = 0.f, ss = 0.f;
#pragma unroll
    for (int i = 0; i < 8; ++i) { s += xv[i]; ss += xv[i] * xv[i]; }
#pragma unroll
    for (int off = 32; off; off >>= 1) {
        s += __shfl_xor(s, off);
        ss += __shfl_xor(ss, off);
    }
    float mean = s * (1.f / 512.f);
    float var = ss * (1.f / 512.f) - mean * mean;
    float rs = rsqrtf(var + 1e-14f);
    float o[8];
#pragma unroll
    for (int i = 0; i < 8; ++i)
        o[i] = (xv[i] - mean) * rs * gamma[l * 8 + i] + beta[l * 8 + i];
    float4 of0 = { o[0], o[1], o[2], o[3] }, of1 = { o[4], o[5], o[6], o[7] };
    *(float4*)&outf[row * 512 + l * 8] = of0;
    *(float4*)&outf[row * 512 + l * 8 + 4] = of1;
}

// ---------------------------------------------------------------------------
extern "C" void kernel_launch(void* const* d_in, const int* in_sizes, int n_in,
                              void* d_out, int out_size, void* d_ws, size_t ws_size,
                              hipStream_t stream)
{
    const float* x      = (const float*)d_in[0];
    const float* Wq     = (const float*)d_in[1];
    const float* bq     = (const float*)d_in[2];
    const float* Wk     = (const float*)d_in[3];
    const float* bk     = (const float*)d_in[4];
    const float* Wv     = (const float*)d_in[5];
    const float* bv     = (const float*)d_in[6];
    const float* gamma1 = (const float*)d_in[7];
    const float* beta1  = (const float*)d_in[8];
    const float* gamma2 = (const float*)d_in[9];
    const float* beta2  = (const float*)d_in[10];
    const float* W1     = (const float*)d_in[11];
    const float* b1     = (const float*)d_in[12];
    const float* W2     = (const float*)d_in[13];
    const float* b2     = (const float*)d_in[14];

    const int B = 4, S = 2048, D = 512, F = 2048;
    const int BS = B * S;  // 8192

    char* w = (char*)d_ws;
    auto alloc = [&](size_t bytes) {
        char* p = w;
        w += (bytes + 255) & ~(size_t)255;
        return p;
    };
    u16* wqkvT = (u16*)alloc((size_t)3 * D * D * 2);   // [1536][512]
    float* bqkv = (float*)alloc((size_t)3 * D * 4);
    u16* w1T = (u16*)alloc((size_t)F * D * 2);         // [F][D]
    u16* w2T = (u16*)alloc((size_t)D * F * 2);         // [D][F]
    u16* xb  = (u16*)alloc((size_t)BS * D * 2);        // reused as hb
    u16* qkvb = (u16*)alloc((size_t)BS * 3 * D * 2);   // [BS][1536]
    u16* vT  = (u16*)alloc((size_t)B * D * S * 2);     // [B][512][2048]
    float* bigA = (float*)alloc((size_t)2 * BS * D * 4); // 32MB: O partials -> f0/f1p
    float* h = (float*)alloc((size_t)BS * D * 4);      // 16MB
    u16* f1  = (u16*)alloc((size_t)BS * F * 2);        // 32MB
    float* ml = (float*)alloc((size_t)4 * BS * 4);     // mArr[2][BS], lArr[2][BS]

    u16* hb = xb;
    float* Op = bigA;                                  // [2][BS][512]
    float* mArr = ml;
    float* lArr = ml + 2 * BS;
    float* f0  = bigA;                                 // FFN2 partial 0 (O dead)
    float* f1p = bigA + (size_t)BS * D;                // FFN2 partial 1

    // 1. effective QKV weights (stacked/transposed) + bias concat
    reduce_qkv_w<<<dim3(D * D / 256), 256, 0, stream>>>(Wq, Wk, Wv, wqkvT);
    concat_bias<<<dim3(6), 256, 0, stream>>>(bq, bk, bv, bqkv);
    // 2-3. W1T [F][D], W2T [D][F]
    transpose_k<true><<<dim3(D / 64, F / 64, 1), 256, 0, stream>>>(
        W1, w1T, F, D, 0, 0);
    transpose_k<true><<<dim3(F / 64, D / 64, 1), 256, 0, stream>>>(
        W2, w2T, D, F, 0, 0);
    // 4. x -> bf16
    cvt_f32_bf16<<<dim3(BS * D / 8 / 256), 256, 0, stream>>>(x, xb, (ll)BS * D);
    // 5. fused qkv = x @ Wqkv^T + bqkv -> [BS][1536]
    gemm2<true><<<dim3(BS / 128, 3 * D / 128, 1), 256, 0, stream>>>(
        xb, wqkvT, qkvb, bqkv, D, D, 3 * D, D, 1, 1.f, 0, 0, 0, 0);
    // 6. vT[b][e][t] = v[b][t][e]
    transpose_k<false><<<dim3(S / 64, D / 64, B), 256, 0, stream>>>(
        qkvb + 2 * D, vT, 3 * D, S, (ll)S * 3 * D, (ll)D * S);
    // 7. fused flash attention (split-KV x2) -> unnormalized partials
    fattn2<<<dim3(S / 32, 2, B), 256, 0, stream>>>(qkvb, vT, Op, mArr, lArr);
    // 8. h = LN(x + merged y) -> fp32 + bf16
    add_ln_merge<<<dim3(BS), 64, 0, stream>>>(x, Op, mArr, lArr,
                                              gamma1, beta1, h, hb);
    // 9. f1 = h @ W1 + b1 (bf16)
    gemm2<true><<<dim3(BS / 128, F / 128, 1), 256, 0, stream>>>(
        hb, w1T, f1, b1, D, D, F, D, 1, 1.f, 0, 0, 0, 0);
    // 10. f2 = f1 @ W2 + b2, split-K=2 -> fp32 partials f0, f1p (O dead)
    gemm2<false><<<dim3(BS / 128, D / 128, 2), 256, 0, stream>>>(
        f1, w2T, f0, b2, F, F, D, F / 2, 2, 1.f, 0, 0, 0, (ll)BS * D);
    // 11. out = LN(h + f0 + f1p)
    add_ln3<<<dim3(BS), 64, 0, stream>>>(h, f0, f1p, gamma2, beta2,
                                         (float*)d_out);
}

// Round 6
// 206.478 us; speedup vs baseline: 1.4527x; 1.1570x over previous
//
#include <hip/hip_runtime.h>

typedef unsigned short u16;
typedef u16 ushort8 __attribute__((ext_vector_type(8)));
typedef __bf16 bf16x8 __attribute__((ext_vector_type(8)));
typedef float f32x4 __attribute__((ext_vector_type(4)));
typedef long long ll;

__device__ __forceinline__ u16 f2bf(float f) {
    unsigned u = __builtin_bit_cast(unsigned, f);
    u += 0x7FFFu + ((u >> 16) & 1u);
    return (u16)(u >> 16);
}

// async global->LDS, 16B per lane, wave-uniform LDS base + lane*16
#define GLOAD16(dst, src) \
    __builtin_amdgcn_global_load_lds( \
        (const __attribute__((address_space(1))) void*)(src), \
        (__attribute__((address_space(3))) void*)(dst), 16, 0, 0)

// ---------------------------------------------------------------------------
// Effective QKV weights, stacked+transposed: rows 0-511 q, 512-1023 k, 1024+ v
// ---------------------------------------------------------------------------
__global__ __launch_bounds__(256) void reduce_qkv_w(
    const float* __restrict__ Wq, const float* __restrict__ Wk,
    const float* __restrict__ Wv, u16* __restrict__ WqkvT)
{
    int idx = blockIdx.x * 256 + threadIdx.x;   // 0 .. 512*512-1
    int e = idx & 511, d = idx >> 9;
    float sq = 0.f, sk = 0.f, sv = 0.f;
#pragma unroll
    for (int h = 0; h < 8; ++h) {
        ll off = (ll)(h * 512 + d) * 512 + e;
        sq += Wq[off]; sk += Wk[off]; sv += Wv[off];
    }
    int o = e * 512 + d;
    WqkvT[o] = f2bf(sq);
    WqkvT[512 * 512 + o] = f2bf(sk);
    WqkvT[1024 * 512 + o] = f2bf(sv);
}

__global__ __launch_bounds__(256) void concat_bias(
    const float* __restrict__ bq, const float* __restrict__ bk,
    const float* __restrict__ bv, float* __restrict__ bqkv)
{
    int i = blockIdx.x * 256 + threadIdx.x;  // 0..1535
    float v = (i < 512) ? bq[i] : (i < 1024 ? bk[i - 512] : bv[i - 1024]);
    bqkv[i] = v;
}

// ---------------------------------------------------------------------------
__global__ __launch_bounds__(256) void cvt_f32_bf16(
    const float* __restrict__ in, u16* __restrict__ out, ll n)
{
    ll i = ((ll)blockIdx.x * 256 + threadIdx.x) * 8;
    if (i >= n) return;
    float4 a = *(const float4*)&in[i];
    float4 b = *(const float4*)&in[i + 4];
    ushort8 o;
    o[0] = f2bf(a.x); o[1] = f2bf(a.y); o[2] = f2bf(a.z); o[3] = f2bf(a.w);
    o[4] = f2bf(b.x); o[5] = f2bf(b.y); o[6] = f2bf(b.z); o[7] = f2bf(b.w);
    *(ushort8*)&out[i] = o;
}

// ---------------------------------------------------------------------------
// 64x64 LDS transpose: out[c][r] = bf16(in[r][c]); grid (R/64, C/64, batch)
// ---------------------------------------------------------------------------
template<bool SRC_F32>
__global__ __launch_bounds__(256) void transpose_k(
    const void* __restrict__ in, u16* __restrict__ out,
    int ldin, int ldout, ll inB, ll outB)
{
    __shared__ u16 tile[64][65];
    int b = blockIdx.z;
    int r0 = blockIdx.x * 64, c0 = blockIdx.y * 64;
#pragma unroll
    for (int i = 0; i < 16; ++i) {
        int lin = threadIdx.x + i * 256;
        int rr = lin >> 6, cc = lin & 63;
        ll src = (ll)b * inB + (ll)(r0 + rr) * ldin + (c0 + cc);
        u16 val = SRC_F32 ? f2bf(((const float*)in)[src]) : ((const u16*)in)[src];
        tile[rr][cc] = val;
    }
    __syncthreads();
#pragma unroll
    for (int i = 0; i < 16; ++i) {
        int lin = threadIdx.x + i * 256;
        int rr = lin >> 6, cc = lin & 63;
        out[(ll)b * outB + (ll)(c0 + rr) * ldout + (r0 + cc)] = tile[cc][rr];
    }
}

// ---------------------------------------------------------------------------
// bf16 MFMA GEMM, m97 structure: 128x128 tile, BK=64, global_load_lds w=16,
// XOR-swizzled LDS (G21: linear LDS dest + swizzled global src + swizzled read)
//   C[M,N](+slice) = alpha * A[M,Kslice] @ Bt[N,Kslice]^T + bias[N] (slice 0)
// grid: (M/128, N/128, batch*nsplit); 256 thr = 4 waves (2x2 of 64x64).
// LDS row = 64 u16 = 128B = 8 chunks of 16B. LDS[R][c] = G[bm+R][c^(R&7)].
// ---------------------------------------------------------------------------
template<bool OUT_BF16>
__global__ __launch_bounds__(256) void gemm3(
    const u16* __restrict__ A, const u16* __restrict__ Bt,
    void* __restrict__ C, const float* __restrict__ bias,
    int lda, int ldb, int ldc, int Kslice, int nsplit, float alpha,
    ll strideA, ll strideB, ll strideC, ll sliceStrideC)
{
    __shared__ __attribute__((aligned(16))) u16 smA[128 * 64];  // 16 KB
    __shared__ __attribute__((aligned(16))) u16 smB[128 * 64];  // 16 KB

    const int z = blockIdx.z;
    const int b = z / nsplit, s = z - b * nsplit;
    A  += (ll)b * strideA + (ll)s * Kslice;
    Bt += (ll)b * strideB + (ll)s * Kslice;
    const ll cbase = (ll)b * strideC + (ll)s * sliceStrideC;

    const int bm = blockIdx.x * 128, bn = blockIdx.y * 128;
    const int t = threadIdx.x, w = t >> 6, l = t & 63;
    const int wm = (w >> 1) * 64, wn = (w & 1) * 64;
    const int lr = l & 15, lg = l >> 4;

    // staging: wave w owns rows [w*32, w*32+32); 4 gloads of 8 rows each.
    // lane l -> LDS row offset l>>3, chunk l&7; global chunk (l&7)^(l>>3)
    const int srow = l >> 3;
    const int schunk = (l & 7) ^ srow;
    const u16* ga = A + (ll)(bm + w * 32 + srow) * lda + schunk * 8;
    const u16* gb = Bt + (ll)(bn + w * 32 + srow) * ldb + schunk * 8;

    f32x4 acc[4][4] = {};

    for (int k0 = 0; k0 < Kslice; k0 += 64) {
#pragma unroll
        for (int g = 0; g < 4; ++g) {
            GLOAD16(&smA[(w * 32 + g * 8) * 64], ga + (ll)(g * 8) * lda);
            GLOAD16(&smB[(w * 32 + g * 8) * 64], gb + (ll)(g * 8) * ldb);
        }
        ga += 64; gb += 64;
        __syncthreads();   // drains vmcnt -> tiles ready

#pragma unroll
        for (int ks = 0; ks < 2; ++ks) {
            bf16x8 af[4], bfr[4];
#pragma unroll
            for (int i = 0; i < 4; ++i) {
                int ra = wm + i * 16 + lr;
                af[i] = *(const bf16x8*)&smA[ra * 64 + ((((ks << 2) | lg)) ^ (ra & 7)) * 8];
            }
#pragma unroll
            for (int i = 0; i < 4; ++i) {
                int rb = wn + i * 16 + lr;
                bfr[i] = *(const bf16x8*)&smB[rb * 64 + ((((ks << 2) | lg)) ^ (rb & 7)) * 8];
            }
#pragma unroll
            for (int mi = 0; mi < 4; ++mi)
#pragma unroll
                for (int ni = 0; ni < 4; ++ni)
                    acc[mi][ni] = __builtin_amdgcn_mfma_f32_16x16x32_bf16(
                        af[mi], bfr[ni], acc[mi][ni], 0, 0, 0);
        }
        __syncthreads();
    }

    // epilogue: C/D mapping col = lane&15, row = (lane>>4)*4 + j
    const bool addb = (bias != nullptr) && (s == 0);
#pragma unroll
    for (int ni = 0; ni < 4; ++ni) {
        const int col = bn + wn + ni * 16 + lr;
        const float bv = addb ? bias[col] : 0.f;
#pragma unroll
        for (int mi = 0; mi < 4; ++mi) {
#pragma unroll
            for (int j = 0; j < 4; ++j) {
                const int row = bm + wm + mi * 16 + lg * 4 + j;
                const ll off = cbase + (ll)row * ldc + col;
                const float v = acc[mi][ni][j] * alpha + bv;
                if (OUT_BF16) ((u16*)C)[off] = f2bf(v);
                else          ((float*)C)[off] = v;
            }
        }
    }
}

// ---------------------------------------------------------------------------
// Row softmax: read fp32 logits, write bf16 probabilities.
// Row length 2048, 256 threads x 8 elems.
// ---------------------------------------------------------------------------
__global__ __launch_bounds__(256) void softmax_f2b(
    const float* __restrict__ in, u16* __restrict__ out, int ncols)
{
    ll row = blockIdx.x;
    const float* rp = in + row * (ll)ncols;
    u16* op = out + row * (ll)ncols;
    int t = threadIdx.x;
    float4 a = *(const float4*)&rp[t * 8];
    float4 b = *(const float4*)&rp[t * 8 + 4];
    float v[8] = { a.x, a.y, a.z, a.w, b.x, b.y, b.z, b.w };
    float m = -1e30f;
#pragma unroll
    for (int i = 0; i < 8; ++i) m = fmaxf(m, v[i]);
#pragma unroll
    for (int off = 32; off; off >>= 1) m = fmaxf(m, __shfl_xor(m, off));
    __shared__ float redm[4], reds[4];
    if ((t & 63) == 0) redm[t >> 6] = m;
    __syncthreads();
    m = fmaxf(fmaxf(redm[0], redm[1]), fmaxf(redm[2], redm[3]));
    float s = 0.f;
#pragma unroll
    for (int i = 0; i < 8; ++i) { v[i] = __expf(v[i] - m); s += v[i]; }
#pragma unroll
    for (int off = 32; off; off >>= 1) s += __shfl_xor(s, off);
    if ((t & 63) == 0) reds[t >> 6] = s;
    __syncthreads();
    s = reds[0] + reds[1] + reds[2] + reds[3];
    float inv = 1.f / s;
    ushort8 o;
#pragma unroll
    for (int i = 0; i < 8; ++i) o[i] = f2bf(v[i] * inv);
    *(ushort8*)&op[t * 8] = o;
}

// ---------------------------------------------------------------------------
// out = LayerNorm(a + b [+ c]) * gamma + beta over rows of 512 (1 wave/row)
// ---------------------------------------------------------------------------
__global__ __launch_bounds__(64) void add_ln3(
    const float* __restrict__ a, const float* __restrict__ b,
    const float* __restrict__ c,
    const float* __restrict__ gamma, const float* __restrict__ beta,
    float* __restrict__ outf, u16* __restrict__ outb)
{
    ll row = blockIdx.x;
    const float* pa = a + row * 512;
    const float* pb = b + row * 512;
    int l = threadIdx.x;
    float4 a0 = *(const float4*)&pa[l * 8], a1 = *(const float4*)&pa[l * 8 + 4];
    float4 b0 = *(const float4*)&pb[l * 8], b1 = *(const float4*)&pb[l * 8 + 4];
    float xv[8] = { a0.x + b0.x, a0.y + b0.y, a0.z + b0.z, a0.w + b0.w,
                    a1.x + b1.x, a1.y + b1.y, a1.z + b1.z, a1.w + b1.w };
    if (c) {
        const float* pc = c + row * 512;
        float4 c0 = *(const float4*)&pc[l * 8], c1 = *(const float4*)&pc[l * 8 + 4];
        xv[0] += c0.x; xv[1] += c0.y; xv[2] += c0.z; xv[3] += c0.w;
        xv[4] += c1.x; xv[5] += c1.y; xv[6] += c1.z; xv[7] += c1.w;
    }
    float s = 0.f, ss = 0.f;
#pragma unroll
    for (int i = 0; i < 8; ++i) { s += xv[i]; ss += xv[i] * xv[i]; }
#pragma unroll
    for (int off = 32; off; off >>= 1) {
        s += __shfl_xor(s, off);
        ss += __shfl_xor(ss, off);
    }
    float mean = s * (1.f / 512.f);
    float var = ss * (1.f / 512.f) - mean * mean;
    float rs = rsqrtf(var + 1e-14f);
    float o[8];
#pragma unroll
    for (int i = 0; i < 8; ++i)
        o[i] = (xv[i] - mean) * rs * gamma[l * 8 + i] + beta[l * 8 + i];
    if (outf) {
        float4 o0 = { o[0], o[1], o[2], o[3] }, o1 = { o[4], o[5], o[6], o[7] };
        *(float4*)&outf[row * 512 + l * 8] = o0;
        *(float4*)&outf[row * 512 + l * 8 + 4] = o1;
    }
    if (outb) {
        ushort8 ob;
#pragma unroll
        for (int i = 0; i < 8; ++i) ob[i] = f2bf(o[i]);
        *(ushort8*)&outb[row * 512 + l * 8] = ob;
    }
}

// ---------------------------------------------------------------------------
extern "C" void kernel_launch(void* const* d_in, const int* in_sizes, int n_in,
                              void* d_out, int out_size, void* d_ws, size_t ws_size,
                              hipStream_t stream)
{
    const float* x      = (const float*)d_in[0];
    const float* Wq     = (const float*)d_in[1];
    const float* bq     = (const float*)d_in[2];
    const float* Wk     = (const float*)d_in[3];
    const float* bk     = (const float*)d_in[4];
    const float* Wv     = (const float*)d_in[5];
    const float* bv     = (const float*)d_in[6];
    const float* gamma1 = (const float*)d_in[7];
    const float* beta1  = (const float*)d_in[8];
    const float* gamma2 = (const float*)d_in[9];
    const float* beta2  = (const float*)d_in[10];
    const float* W1     = (const float*)d_in[11];
    const float* b1     = (const float*)d_in[12];
    const float* W2     = (const float*)d_in[13];
    const float* b2     = (const float*)d_in[14];

    const int B = 4, S = 2048, D = 512, F = 2048;
    const int BS = B * S;  // 8192

    char* w = (char*)d_ws;
    auto alloc = [&](size_t bytes) {
        char* p = w;
        w += (bytes + 255) & ~(size_t)255;
        return p;
    };
    u16* wqkvT = (u16*)alloc((size_t)3 * D * D * 2);   // [1536][512]
    float* bqkv = (float*)alloc((size_t)3 * D * 4);
    u16* w1T = (u16*)alloc((size_t)F * D * 2);         // [F][D]
    u16* w2T = (u16*)alloc((size_t)D * F * 2);         // [D][F]
    u16* xb  = (u16*)alloc((size_t)BS * D * 2);        // reused as hb
    u16* qkvb = (u16*)alloc((size_t)BS * 3 * D * 2);   // [BS][1536]
    u16* attnb = (u16*)alloc((size_t)B * S * S * 2);   // 32MB; reused as f1
    float* big = (float*)alloc((size_t)B * S * S * 4); // 64MB overlay region

    // overlay plan inside `big` (scoresF dead after softmax):
    float* scoresF = big;                              // [B,S,S]    steps 6-7
    float* y0 = big;                                   // [BS,D]     step 9+
    float* y1 = big + (size_t)BS * D;                  // [BS,D]
    float* h  = big + (size_t)2 * BS * D;              // [BS,D] 32-48MB
    u16* vT   = (u16*)((char*)big + (size_t)48 * 1024 * 1024);  // [B,D,S] 8MB
    float* f0 = y0;                                    // FFN2 partials (y dead)
    float* f1p = y1;
    u16* hb = xb;
    u16* f1 = attnb;                                   // [BS,F] bf16 (attn dead)

    // 1. effective QKV weights (stacked/transposed) + bias concat
    reduce_qkv_w<<<dim3(D * D / 256), 256, 0, stream>>>(Wq, Wk, Wv, wqkvT);
    concat_bias<<<dim3(6), 256, 0, stream>>>(bq, bk, bv, bqkv);
    // 2-3. W1T [F][D], W2T [D][F]
    transpose_k<true><<<dim3(D / 64, F / 64, 1), 256, 0, stream>>>(
        W1, w1T, F, D, 0, 0);
    transpose_k<true><<<dim3(F / 64, D / 64, 1), 256, 0, stream>>>(
        W2, w2T, D, F, 0, 0);
    // 4. x -> bf16
    cvt_f32_bf16<<<dim3(BS * D / 8 / 256), 256, 0, stream>>>(x, xb, (ll)BS * D);
    // 5. fused qkv = x @ Wqkv^T + bqkv -> [BS][1536]
    gemm3<true><<<dim3(BS / 128, 3 * D / 128, 1), 256, 0, stream>>>(
        xb, wqkvT, qkvb, bqkv, D, D, 3 * D, D, 1, 1.f, 0, 0, 0, 0);
    // 6. scores = q @ k^T / 8 -> fp32 (full logit precision)
    gemm3<false><<<dim3(S / 128, S / 128, B), 256, 0, stream>>>(
        qkvb, qkvb + D, scoresF, nullptr, 3 * D, 3 * D, S, D, 1, 0.125f,
        (ll)S * 3 * D, (ll)S * 3 * D, (ll)S * S, 0);
    // 7. softmax: fp32 logits -> bf16 probs
    softmax_f2b<<<dim3(B * S), 256, 0, stream>>>(scoresF, attnb, S);
    // 8. vT[b][e][t] = v[b][t][e]  (scoresF dead; vT at big+48MB)
    transpose_k<false><<<dim3(S / 64, D / 64, B), 256, 0, stream>>>(
        qkvb + 2 * D, vT, 3 * D, S, (ll)S * 3 * D, (ll)D * S);
    // 9. y = attn @ v, split-K=2 -> fp32 partials y0,y1 (overlay scoresF)
    gemm3<false><<<dim3(S / 128, D / 128, B * 2), 256, 0, stream>>>(
        attnb, vT, y0, nullptr, S, S, D, S / 2, 2, 1.f,
        (ll)S * S, (ll)D * S, (ll)S * D, (ll)BS * D);
    // 10. h = LN(x + y0 + y1) -> fp32 + bf16
    add_ln3<<<dim3(BS), 64, 0, stream>>>(x, y0, y1, gamma1, beta1, h, hb);
    // 11. f1 = h @ W1 + b1 (bf16; overlays attnb)
    gemm3<true><<<dim3(BS / 128, F / 128, 1), 256, 0, stream>>>(
        hb, w1T, f1, b1, D, D, F, D, 1, 1.f, 0, 0, 0, 0);
    // 12. f2 = f1 @ W2 + b2, split-K=2 -> fp32 partials f0, f1p (y dead)
    gemm3<false><<<dim3(BS / 128, D / 128, 2), 256, 0, stream>>>(
        f1, w2T, f0, b2, F, F, D, F / 2, 2, 1.f, 0, 0, 0, (ll)BS * D);
    // 13. out = LN(h + f0 + f1p)
    add_ln3<<<dim3(BS), 64, 0, stream>>>(h, f0, f1p, gamma2, beta2,
                                         (float*)d_out, nullptr);
}

// Round 7
// 193.747 us; speedup vs baseline: 1.5481x; 1.0657x over previous
//
#include <hip/hip_runtime.h>

typedef unsigned short u16;
typedef u16 ushort8 __attribute__((ext_vector_type(8)));
typedef __bf16 bf16x8 __attribute__((ext_vector_type(8)));
typedef float f32x4 __attribute__((ext_vector_type(4)));
typedef long long ll;

__device__ __forceinline__ u16 f2bf(float f) {
    unsigned u = __builtin_bit_cast(unsigned, f);
    u += 0x7FFFu + ((u >> 16) & 1u);
    return (u16)(u >> 16);
}
__device__ __forceinline__ float bf2f(u16 h) {
    return __builtin_bit_cast(float, (unsigned)h << 16);
}

// async global->LDS, 16B per lane, wave-uniform LDS base + lane*16
#define GLOAD16(dst, src) \
    __builtin_amdgcn_global_load_lds( \
        (const __attribute__((address_space(1))) void*)(src), \
        (__attribute__((address_space(3))) void*)(dst), 16, 0, 0)

// ---------------------------------------------------------------------------
// Effective QKV weights, stacked+transposed: rows 0-511 q, 512-1023 k, 1024+ v
// ---------------------------------------------------------------------------
__global__ __launch_bounds__(256) void reduce_qkv_w(
    const float* __restrict__ Wq, const float* __restrict__ Wk,
    const float* __restrict__ Wv, u16* __restrict__ WqkvT)
{
    int idx = blockIdx.x * 256 + threadIdx.x;   // 0 .. 512*512-1
    int e = idx & 511, d = idx >> 9;
    float sq = 0.f, sk = 0.f, sv = 0.f;
#pragma unroll
    for (int h = 0; h < 8; ++h) {
        ll off = (ll)(h * 512 + d) * 512 + e;
        sq += Wq[off]; sk += Wk[off]; sv += Wv[off];
    }
    int o = e * 512 + d;
    WqkvT[o] = f2bf(sq);
    WqkvT[512 * 512 + o] = f2bf(sk);
    WqkvT[1024 * 512 + o] = f2bf(sv);
}

__global__ __launch_bounds__(256) void concat_bias(
    const float* __restrict__ bq, const float* __restrict__ bk,
    const float* __restrict__ bv, float* __restrict__ bqkv)
{
    int i = blockIdx.x * 256 + threadIdx.x;  // 0..1535
    float v = (i < 512) ? bq[i] : (i < 1024 ? bk[i - 512] : bv[i - 1024]);
    bqkv[i] = v;
}

// ---------------------------------------------------------------------------
__global__ __launch_bounds__(256) void cvt_f32_bf16(
    const float* __restrict__ in, u16* __restrict__ out, ll n)
{
    ll i = ((ll)blockIdx.x * 256 + threadIdx.x) * 8;
    if (i >= n) return;
    float4 a = *(const float4*)&in[i];
    float4 b = *(const float4*)&in[i + 4];
    ushort8 o;
    o[0] = f2bf(a.x); o[1] = f2bf(a.y); o[2] = f2bf(a.z); o[3] = f2bf(a.w);
    o[4] = f2bf(b.x); o[5] = f2bf(b.y); o[6] = f2bf(b.z); o[7] = f2bf(b.w);
    *(ushort8*)&out[i] = o;
}

// ---------------------------------------------------------------------------
// 64x64 LDS transpose: out[c][r] = bf16(in[r][c]); grid (R/64, C/64, batch)
// ---------------------------------------------------------------------------
template<bool SRC_F32>
__global__ __launch_bounds__(256) void transpose_k(
    const void* __restrict__ in, u16* __restrict__ out,
    int ldin, int ldout, ll inB, ll outB)
{
    __shared__ u16 tile[64][65];
    int b = blockIdx.z;
    int r0 = blockIdx.x * 64, c0 = blockIdx.y * 64;
#pragma unroll
    for (int i = 0; i < 16; ++i) {
        int lin = threadIdx.x + i * 256;
        int rr = lin >> 6, cc = lin & 63;
        ll src = (ll)b * inB + (ll)(r0 + rr) * ldin + (c0 + cc);
        u16 val = SRC_F32 ? f2bf(((const float*)in)[src]) : ((const u16*)in)[src];
        tile[rr][cc] = val;
    }
    __syncthreads();
#pragma unroll
    for (int i = 0; i < 16; ++i) {
        int lin = threadIdx.x + i * 256;
        int rr = lin >> 6, cc = lin & 63;
        out[(ll)b * outB + (ll)(c0 + rr) * ldout + (r0 + cc)] = tile[cc][rr];
    }
}

// ---------------------------------------------------------------------------
// bf16 MFMA GEMM, m97 structure: 128x128 tile, BK=64, global_load_lds w=16,
// XOR-swizzled LDS. EPI: 0 = fp32 out, 1 = bf16 out, 2 = bf16(exp(alpha*v))
// (no-max exp is safe: |logits| <= ~26 -> exp in [5e-12, 2e11], fp32/bf16 ok)
// grid: (M/128, N/128, batch*nsplit); 256 thr = 4 waves (2x2 of 64x64).
// ---------------------------------------------------------------------------
template<int EPI>
__global__ __launch_bounds__(256) void gemm3(
    const u16* __restrict__ A, const u16* __restrict__ Bt,
    void* __restrict__ C, const float* __restrict__ bias,
    int lda, int ldb, int ldc, int Kslice, int nsplit, float alpha,
    ll strideA, ll strideB, ll strideC, ll sliceStrideC)
{
    __shared__ __attribute__((aligned(16))) u16 smA[128 * 64];  // 16 KB
    __shared__ __attribute__((aligned(16))) u16 smB[128 * 64];  // 16 KB

    const int z = blockIdx.z;
    const int b = z / nsplit, s = z - b * nsplit;
    A  += (ll)b * strideA + (ll)s * Kslice;
    Bt += (ll)b * strideB + (ll)s * Kslice;
    const ll cbase = (ll)b * strideC + (ll)s * sliceStrideC;

    const int bm = blockIdx.x * 128, bn = blockIdx.y * 128;
    const int t = threadIdx.x, w = t >> 6, l = t & 63;
    const int wm = (w >> 1) * 64, wn = (w & 1) * 64;
    const int lr = l & 15, lg = l >> 4;

    // staging: wave w owns rows [w*32, w*32+32); 4 gloads of 8 rows each.
    // lane l -> LDS row offset l>>3, chunk l&7; global chunk (l&7)^(l>>3)
    const int srow = l >> 3;
    const int schunk = (l & 7) ^ srow;
    const u16* ga = A + (ll)(bm + w * 32 + srow) * lda + schunk * 8;
    const u16* gb = Bt + (ll)(bn + w * 32 + srow) * ldb + schunk * 8;

    f32x4 acc[4][4] = {};

    for (int k0 = 0; k0 < Kslice; k0 += 64) {
#pragma unroll
        for (int g = 0; g < 4; ++g) {
            GLOAD16(&smA[(w * 32 + g * 8) * 64], ga + (ll)(g * 8) * lda);
            GLOAD16(&smB[(w * 32 + g * 8) * 64], gb + (ll)(g * 8) * ldb);
        }
        ga += 64; gb += 64;
        __syncthreads();   // drains vmcnt -> tiles ready

#pragma unroll
        for (int ks = 0; ks < 2; ++ks) {
            bf16x8 af[4], bfr[4];
#pragma unroll
            for (int i = 0; i < 4; ++i) {
                int ra = wm + i * 16 + lr;
                af[i] = *(const bf16x8*)&smA[ra * 64 + ((((ks << 2) | lg)) ^ (ra & 7)) * 8];
            }
#pragma unroll
            for (int i = 0; i < 4; ++i) {
                int rb = wn + i * 16 + lr;
                bfr[i] = *(const bf16x8*)&smB[rb * 64 + ((((ks << 2) | lg)) ^ (rb & 7)) * 8];
            }
#pragma unroll
            for (int mi = 0; mi < 4; ++mi)
#pragma unroll
                for (int ni = 0; ni < 4; ++ni)
                    acc[mi][ni] = __builtin_amdgcn_mfma_f32_16x16x32_bf16(
                        af[mi], bfr[ni], acc[mi][ni], 0, 0, 0);
        }
        __syncthreads();
    }

    // epilogue: C/D mapping col = lane&15, row = (lane>>4)*4 + j
    const bool addb = (bias != nullptr) && (s == 0);
#pragma unroll
    for (int ni = 0; ni < 4; ++ni) {
        const int col = bn + wn + ni * 16 + lr;
        const float bv = addb ? bias[col] : 0.f;
#pragma unroll
        for (int mi = 0; mi < 4; ++mi) {
#pragma unroll
            for (int j = 0; j < 4; ++j) {
                const int row = bm + wm + mi * 16 + lg * 4 + j;
                const ll off = cbase + (ll)row * ldc + col;
                float v = acc[mi][ni][j] * alpha + bv;
                if (EPI == 2) v = __expf(v);
                if (EPI == 0) ((float*)C)[off] = v;
                else          ((u16*)C)[off] = f2bf(v);
            }
        }
    }
}

// ---------------------------------------------------------------------------
// Row sums of bf16 matrix rows (length 2048): l[row] = sum(P~[row,:]) in fp32
// ---------------------------------------------------------------------------
__global__ __launch_bounds__(256) void rowsum_bf16(
    const u16* __restrict__ p, float* __restrict__ lrow, int ncols)
{
    ll row = blockIdx.x;
    const u16* rp = p + row * (ll)ncols;
    int t = threadIdx.x;
    ushort8 raw = *(const ushort8*)&rp[t * 8];
    float s = 0.f;
#pragma unroll
    for (int i = 0; i < 8; ++i) s += bf2f(raw[i]);
#pragma unroll
    for (int off = 32; off; off >>= 1) s += __shfl_xor(s, off);
    __shared__ float reds[4];
    if ((t & 63) == 0) reds[t >> 6] = s;
    __syncthreads();
    if (t == 0) lrow[row] = reds[0] + reds[1] + reds[2] + reds[3];
}

// ---------------------------------------------------------------------------
// out = LayerNorm(a + (b [+ c]) * (rowdiv ? 1/rowdiv[row] : 1)) * gamma + beta
// rows of 512, 1 wave/row.
// ---------------------------------------------------------------------------
__global__ __launch_bounds__(64) void add_ln3(
    const float* __restrict__ a, const float* __restrict__ b,
    const float* __restrict__ c, const float* __restrict__ rowdiv,
    const float* __restrict__ gamma, const float* __restrict__ beta,
    float* __restrict__ outf, u16* __restrict__ outb)
{
    ll row = blockIdx.x;
    const float* pa = a + row * 512;
    const float* pb = b + row * 512;
    int l = threadIdx.x;
    float4 a0 = *(const float4*)&pa[l * 8], a1 = *(const float4*)&pa[l * 8 + 4];
    float4 b0 = *(const float4*)&pb[l * 8], b1 = *(const float4*)&pb[l * 8 + 4];
    float yv[8] = { b0.x, b0.y, b0.z, b0.w, b1.x, b1.y, b1.z, b1.w };
    if (c) {
        const float* pc = c + row * 512;
        float4 c0 = *(const float4*)&pc[l * 8], c1 = *(const float4*)&pc[l * 8 + 4];
        yv[0] += c0.x; yv[1] += c0.y; yv[2] += c0.z; yv[3] += c0.w;
        yv[4] += c1.x; yv[5] += c1.y; yv[6] += c1.z; yv[7] += c1.w;
    }
    float inv = rowdiv ? (1.f / rowdiv[row]) : 1.f;
    float xa[8] = { a0.x, a0.y, a0.z, a0.w, a1.x, a1.y, a1.z, a1.w };
    float xv[8];
#pragma unroll
    for (int i = 0; i < 8; ++i) xv[i] = xa[i] + yv[i] * inv;
    float s = 0.f, ss = 0.f;
#pragma unroll
    for (int i = 0; i < 8; ++i) { s += xv[i]; ss += xv[i] * xv[i]; }
#pragma unroll
    for (int off = 32; off; off >>= 1) {
        s += __shfl_xor(s, off);
        ss += __shfl_xor(ss, off);
    }
    float mean = s * (1.f / 512.f);
    float var = ss * (1.f / 512.f) - mean * mean;
    float rs = rsqrtf(var + 1e-14f);
    float o[8];
#pragma unroll
    for (int i = 0; i < 8; ++i)
        o[i] = (xv[i] - mean) * rs * gamma[l * 8 + i] + beta[l * 8 + i];
    if (outf) {
        float4 o0 = { o[0], o[1], o[2], o[3] }, o1 = { o[4], o[5], o[6], o[7] };
        *(float4*)&outf[row * 512 + l * 8] = o0;
        *(float4*)&outf[row * 512 + l * 8 + 4] = o1;
    }
    if (outb) {
        ushort8 ob;
#pragma unroll
        for (int i = 0; i < 8; ++i) ob[i] = f2bf(o[i]);
        *(ushort8*)&outb[row * 512 + l * 8] = ob;
    }
}

// ---------------------------------------------------------------------------
extern "C" void kernel_launch(void* const* d_in, const int* in_sizes, int n_in,
                              void* d_out, int out_size, void* d_ws, size_t ws_size,
                              hipStream_t stream)
{
    const float* x      = (const float*)d_in[0];
    const float* Wq     = (const float*)d_in[1];
    const float* bq     = (const float*)d_in[2];
    const float* Wk     = (const float*)d_in[3];
    const float* bk     = (const float*)d_in[4];
    const float* Wv     = (const float*)d_in[5];
    const float* bv     = (const float*)d_in[6];
    const float* gamma1 = (const float*)d_in[7];
    const float* beta1  = (const float*)d_in[8];
    const float* gamma2 = (const float*)d_in[9];
    const float* beta2  = (const float*)d_in[10];
    const float* W1     = (const float*)d_in[11];
    const float* b1     = (const float*)d_in[12];
    const float* W2     = (const float*)d_in[13];
    const float* b2     = (const float*)d_in[14];

    const int B = 4, S = 2048, D = 512, F = 2048;
    const int BS = B * S;  // 8192

    char* w = (char*)d_ws;
    auto alloc = [&](size_t bytes) {
        char* p = w;
        w += (bytes + 255) & ~(size_t)255;
        return p;
    };
    u16* wqkvT = (u16*)alloc((size_t)3 * D * D * 2);   // [1536][512]
    float* bqkv = (float*)alloc((size_t)3 * D * 4);
    u16* w1T = (u16*)alloc((size_t)F * D * 2);         // [F][D]
    u16* w2T = (u16*)alloc((size_t)D * F * 2);         // [D][F]
    u16* xb  = (u16*)alloc((size_t)BS * D * 2);        // reused as hb
    u16* qkvb = (u16*)alloc((size_t)BS * 3 * D * 2);   // [BS][1536]
    u16* attnb = (u16*)alloc((size_t)B * S * S * 2);   // 32MB P~; reused as f1
    float* big = (float*)alloc((size_t)B * S * S * 4); // 64MB overlay region
    float* lrow = (float*)alloc((size_t)BS * 4);       // row sums of P~

    // overlay plan inside `big`:
    float* y0 = big;                                   // [BS,D] PV partial 0
    float* y1 = big + (size_t)BS * D;                  // [BS,D] PV partial 1
    float* h  = big + (size_t)2 * BS * D;              // [BS,D]
    u16* vT   = (u16*)((char*)big + (size_t)48 * 1024 * 1024);  // [B,D,S] 8MB
    float* f0 = y0;                                    // FFN2 partials (y dead)
    float* f1p = y1;
    u16* hb = xb;
    u16* f1 = attnb;                                   // [BS,F] bf16 (P~ dead)

    // 1. effective QKV weights (stacked/transposed) + bias concat
    reduce_qkv_w<<<dim3(D * D / 256), 256, 0, stream>>>(Wq, Wk, Wv, wqkvT);
    concat_bias<<<dim3(6), 256, 0, stream>>>(bq, bk, bv, bqkv);
    // 2-3. W1T [F][D], W2T [D][F]
    transpose_k<true><<<dim3(D / 64, F / 64, 1), 256, 0, stream>>>(
        W1, w1T, F, D, 0, 0);
    transpose_k<true><<<dim3(F / 64, D / 64, 1), 256, 0, stream>>>(
        W2, w2T, D, F, 0, 0);
    // 4. x -> bf16
    cvt_f32_bf16<<<dim3(BS * D / 8 / 256), 256, 0, stream>>>(x, xb, (ll)BS * D);
    // 5. fused qkv = x @ Wqkv^T + bqkv -> [BS][1536]
    gemm3<1><<<dim3(BS / 128, 3 * D / 128, 1), 256, 0, stream>>>(
        xb, wqkvT, qkvb, bqkv, D, D, 3 * D, D, 1, 1.f, 0, 0, 0, 0);
    // 6. P~ = exp(q @ k^T / 8) -> bf16 directly (no-max softmax numerator)
    gemm3<2><<<dim3(S / 128, S / 128, B), 256, 0, stream>>>(
        qkvb, qkvb + D, attnb, nullptr, 3 * D, 3 * D, S, D, 1, 0.125f,
        (ll)S * 3 * D, (ll)S * 3 * D, (ll)S * S, 0);
    // 7. l[row] = sum of P~ row
    rowsum_bf16<<<dim3(BS), 256, 0, stream>>>(attnb, lrow, S);
    // 8. vT[b][e][t] = v[b][t][e]
    transpose_k<false><<<dim3(S / 64, D / 64, B), 256, 0, stream>>>(
        qkvb + 2 * D, vT, 3 * D, S, (ll)S * 3 * D, (ll)D * S);
    // 9. y~ = P~ @ v, split-K=2 -> fp32 partials y0,y1
    gemm3<0><<<dim3(S / 128, D / 128, B * 2), 256, 0, stream>>>(
        attnb, vT, y0, nullptr, S, S, D, S / 2, 2, 1.f,
        (ll)S * S, (ll)D * S, (ll)S * D, (ll)BS * D);
    // 10. h = LN(x + (y0+y1)/l) -> fp32 + bf16
    add_ln3<<<dim3(BS), 64, 0, stream>>>(x, y0, y1, lrow, gamma1, beta1, h, hb);
    // 11. f1 = h @ W1 + b1 (bf16; overlays attnb)
    gemm3<1><<<dim3(BS / 128, F / 128, 1), 256, 0, stream>>>(
        hb, w1T, f1, b1, D, D, F, D, 1, 1.f, 0, 0, 0, 0);
    // 12. f2 = f1 @ W2 + b2, split-K=2 -> fp32 partials f0, f1p (y dead)
    gemm3<0><<<dim3(BS / 128, D / 128, 2), 256, 0, stream>>>(
        f1, w2T, f0, b2, F, F, D, F / 2, 2, 1.f, 0, 0, 0, (ll)BS * D);
    // 13. out = LN(h + f0 + f1p)
    add_ln3<<<dim3(BS), 64, 0, stream>>>(h, f0, f1p, nullptr, gamma2, beta2,
                                         (float*)d_out, nullptr);
}

// Round 8
// 182.933 us; speedup vs baseline: 1.6396x; 1.0591x over previous
//
#include <hip/hip_runtime.h>

typedef unsigned short u16;
typedef u16 ushort8 __attribute__((ext_vector_type(8)));
typedef __bf16 bf16x8 __attribute__((ext_vector_type(8)));
typedef float f32x4 __attribute__((ext_vector_type(4)));
typedef long long ll;

__device__ __forceinline__ u16 f2bf(float f) {
    unsigned u = __builtin_bit_cast(unsigned, f);
    u += 0x7FFFu + ((u >> 16) & 1u);
    return (u16)(u >> 16);
}
__device__ __forceinline__ float bf2f(u16 h) {
    return __builtin_bit_cast(float, (unsigned)h << 16);
}

// async global->LDS, 16B per lane, wave-uniform LDS base + lane*16
#define GLOAD16(dst, src) \
    __builtin_amdgcn_global_load_lds( \
        (const __attribute__((address_space(1))) void*)(src), \
        (__attribute__((address_space(3))) void*)(dst), 16, 0, 0)

// ---------------------------------------------------------------------------
// Effective QKV weights, stacked+transposed: rows 0-511 q, 512-1023 k, 1024+ v
// ---------------------------------------------------------------------------
__global__ __launch_bounds__(256) void reduce_qkv_w(
    const float* __restrict__ Wq, const float* __restrict__ Wk,
    const float* __restrict__ Wv, u16* __restrict__ WqkvT)
{
    int idx = blockIdx.x * 256 + threadIdx.x;   // 0 .. 512*512-1
    int e = idx & 511, d = idx >> 9;
    float sq = 0.f, sk = 0.f, sv = 0.f;
#pragma unroll
    for (int h = 0; h < 8; ++h) {
        ll off = (ll)(h * 512 + d) * 512 + e;
        sq += Wq[off]; sk += Wk[off]; sv += Wv[off];
    }
    int o = e * 512 + d;
    WqkvT[o] = f2bf(sq);
    WqkvT[512 * 512 + o] = f2bf(sk);
    WqkvT[1024 * 512 + o] = f2bf(sv);
}

__global__ __launch_bounds__(256) void concat_bias(
    const float* __restrict__ bq, const float* __restrict__ bk,
    const float* __restrict__ bv, float* __restrict__ bqkv)
{
    int i = blockIdx.x * 256 + threadIdx.x;  // 0..1535
    float v = (i < 512) ? bq[i] : (i < 1024 ? bk[i - 512] : bv[i - 1024]);
    bqkv[i] = v;
}

// ---------------------------------------------------------------------------
__global__ __launch_bounds__(256) void cvt_f32_bf16(
    const float* __restrict__ in, u16* __restrict__ out, ll n)
{
    ll i = ((ll)blockIdx.x * 256 + threadIdx.x) * 8;
    if (i >= n) return;
    float4 a = *(const float4*)&in[i];
    float4 b = *(const float4*)&in[i + 4];
    ushort8 o;
    o[0] = f2bf(a.x); o[1] = f2bf(a.y); o[2] = f2bf(a.z); o[3] = f2bf(a.w);
    o[4] = f2bf(b.x); o[5] = f2bf(b.y); o[6] = f2bf(b.z); o[7] = f2bf(b.w);
    *(ushort8*)&out[i] = o;
}

// ---------------------------------------------------------------------------
// 64x64 LDS transpose: out[c][r] = bf16(in[r][c]); grid (R/64, C/64, batch)
// ---------------------------------------------------------------------------
template<bool SRC_F32>
__global__ __launch_bounds__(256) void transpose_k(
    const void* __restrict__ in, u16* __restrict__ out,
    int ldin, int ldout, ll inB, ll outB)
{
    __shared__ u16 tile[64][65];
    int b = blockIdx.z;
    int r0 = blockIdx.x * 64, c0 = blockIdx.y * 64;
#pragma unroll
    for (int i = 0; i < 16; ++i) {
        int lin = threadIdx.x + i * 256;
        int rr = lin >> 6, cc = lin & 63;
        ll src = (ll)b * inB + (ll)(r0 + rr) * ldin + (c0 + cc);
        u16 val = SRC_F32 ? f2bf(((const float*)in)[src]) : ((const u16*)in)[src];
        tile[rr][cc] = val;
    }
    __syncthreads();
#pragma unroll
    for (int i = 0; i < 16; ++i) {
        int lin = threadIdx.x + i * 256;
        int rr = lin >> 6, cc = lin & 63;
        out[(ll)b * outB + (ll)(c0 + rr) * ldout + (r0 + cc)] = tile[cc][rr];
    }
}

// ---------------------------------------------------------------------------
// bf16 MFMA GEMM, m97 structure: 128x128 tile, BK=64, global_load_lds w=16,
// XOR-swizzled LDS. EPI: 0 = fp32 out, 1 = bf16 out, 2 = bf16(exp(alpha*v))
// with per-block row-sum partials written to lpart[blockIdx.y][globalRow].
// (no-max exp is safe: |logits| <= ~26 -> exp in [5e-12, 2e11], fp32/bf16 ok)
// grid: (M/128, N/128, batch*nsplit); 256 thr = 4 waves (2x2 of 64x64).
// ---------------------------------------------------------------------------
template<int EPI>
__global__ __launch_bounds__(256) void gemm3(
    const u16* __restrict__ A, const u16* __restrict__ Bt,
    void* __restrict__ C, const float* __restrict__ bias,
    float* __restrict__ lpart,
    int lda, int ldb, int ldc, int Kslice, int nsplit, float alpha,
    ll strideA, ll strideB, ll strideC, ll sliceStrideC)
{
    __shared__ __attribute__((aligned(16))) u16 smA[128 * 64];  // 16 KB
    __shared__ __attribute__((aligned(16))) u16 smB[128 * 64];  // 16 KB

    const int z = blockIdx.z;
    const int b = z / nsplit, s = z - b * nsplit;
    A  += (ll)b * strideA + (ll)s * Kslice;
    Bt += (ll)b * strideB + (ll)s * Kslice;
    const ll cbase = (ll)b * strideC + (ll)s * sliceStrideC;

    const int bm = blockIdx.x * 128, bn = blockIdx.y * 128;
    const int t = threadIdx.x, w = t >> 6, l = t & 63;
    const int wm = (w >> 1) * 64, wn = (w & 1) * 64;
    const int lr = l & 15, lg = l >> 4;

    // staging: wave w owns rows [w*32, w*32+32); 4 gloads of 8 rows each.
    // lane l -> LDS row offset l>>3, chunk l&7; global chunk (l&7)^(l>>3)
    const int srow = l >> 3;
    const int schunk = (l & 7) ^ srow;
    const u16* ga = A + (ll)(bm + w * 32 + srow) * lda + schunk * 8;
    const u16* gb = Bt + (ll)(bn + w * 32 + srow) * ldb + schunk * 8;

    f32x4 acc[4][4] = {};

    for (int k0 = 0; k0 < Kslice; k0 += 64) {
#pragma unroll
        for (int g = 0; g < 4; ++g) {
            GLOAD16(&smA[(w * 32 + g * 8) * 64], ga + (ll)(g * 8) * lda);
            GLOAD16(&smB[(w * 32 + g * 8) * 64], gb + (ll)(g * 8) * ldb);
        }
        ga += 64; gb += 64;
        __syncthreads();   // drains vmcnt -> tiles ready

#pragma unroll
        for (int ks = 0; ks < 2; ++ks) {
            bf16x8 af[4], bfr[4];
#pragma unroll
            for (int i = 0; i < 4; ++i) {
                int ra = wm + i * 16 + lr;
                af[i] = *(const bf16x8*)&smA[ra * 64 + ((((ks << 2) | lg)) ^ (ra & 7)) * 8];
            }
#pragma unroll
            for (int i = 0; i < 4; ++i) {
                int rb = wn + i * 16 + lr;
                bfr[i] = *(const bf16x8*)&smB[rb * 64 + ((((ks << 2) | lg)) ^ (rb & 7)) * 8];
            }
#pragma unroll
            for (int mi = 0; mi < 4; ++mi)
#pragma unroll
                for (int ni = 0; ni < 4; ++ni)
                    acc[mi][ni] = __builtin_amdgcn_mfma_f32_16x16x32_bf16(
                        af[mi], bfr[ni], acc[mi][ni], 0, 0, 0);
        }
        __syncthreads();
    }

    // epilogue: C/D mapping col = lane&15, row = (lane>>4)*4 + j
    const bool addb = (bias != nullptr) && (s == 0);
    float rs[4][4] = {};   // per-(mi,j) partial row sums (EPI==2 only)
#pragma unroll
    for (int ni = 0; ni < 4; ++ni) {
        const int col = bn + wn + ni * 16 + lr;
        const float bv = addb ? bias[col] : 0.f;
#pragma unroll
        for (int mi = 0; mi < 4; ++mi) {
#pragma unroll
            for (int j = 0; j < 4; ++j) {
                const int row = bm + wm + mi * 16 + lg * 4 + j;
                const ll off = cbase + (ll)row * ldc + col;
                float v = acc[mi][ni][j] * alpha + bv;
                if (EPI == 2) { v = __expf(v); rs[mi][j] += v; }
                if (EPI == 0) ((float*)C)[off] = v;
                else          ((u16*)C)[off] = f2bf(v);
            }
        }
    }

    if (EPI == 2) {
        // reduce rs across the 16 lr lanes, combine col-half waves via LDS,
        // write one 128-row partial-sum vector per block.
        float* lsum = (float*)smA;   // 256 floats (K-loop ended with barrier)
#pragma unroll
        for (int mi = 0; mi < 4; ++mi)
#pragma unroll
            for (int j = 0; j < 4; ++j) {
                float s2 = rs[mi][j];
                s2 += __shfl_xor(s2, 1);
                s2 += __shfl_xor(s2, 2);
                s2 += __shfl_xor(s2, 4);
                s2 += __shfl_xor(s2, 8);
                if (lr == 0)
                    lsum[(w & 1) * 128 + wm + mi * 16 + lg * 4 + j] = s2;
            }
        __syncthreads();
        if (t < 128)
            lpart[(ll)blockIdx.y * 8192 + (ll)b * 2048 + bm + t] =
                lsum[t] + lsum[128 + t];
    }
}

// ---------------------------------------------------------------------------
// h = LN(x + (y0+y1)/l) where l = sum of 16 lpart partials; y0/y1 bf16.
// rows of 512, 1 wave/row. Writes h fp32 + hb bf16.
// ---------------------------------------------------------------------------
__global__ __launch_bounds__(64) void add_ln_attn(
    const float* __restrict__ x, const u16* __restrict__ y0,
    const u16* __restrict__ y1, const float* __restrict__ lpart,
    const float* __restrict__ gamma, const float* __restrict__ beta,
    float* __restrict__ h, u16* __restrict__ hb)
{
    ll row = blockIdx.x;
    int l = threadIdx.x;
    float lsum = 0.f;
#pragma unroll
    for (int j = 0; j < 16; ++j) lsum += lpart[j * 8192 + row];  // uniform
    float inv = 1.f / lsum;
    const float* px = x + row * 512;
    float4 x0 = *(const float4*)&px[l * 8], x1 = *(const float4*)&px[l * 8 + 4];
    ushort8 a = *(const ushort8*)&y0[row * 512 + l * 8];
    ushort8 bv = *(const ushort8*)&y1[row * 512 + l * 8];
    float xa[8] = { x0.x, x0.y, x0.z, x0.w, x1.x, x1.y, x1.z, x1.w };
    float xv[8];
#pragma unroll
    for (int i = 0; i < 8; ++i)
        xv[i] = xa[i] + (bf2f(a[i]) + bf2f(bv[i])) * inv;
    float s = 0.f, ss = 0.f;
#pragma unroll
    for (int i = 0; i < 8; ++i) { s += xv[i]; ss += xv[i] * xv[i]; }
#pragma unroll
    for (int off = 32; off; off >>= 1) {
        s += __shfl_xor(s, off);
        ss += __shfl_xor(ss, off);
    }
    float mean = s * (1.f / 512.f);
    float var = ss * (1.f / 512.f) - mean * mean;
    float rsq = rsqrtf(var + 1e-14f);
    float o[8];
#pragma unroll
    for (int i = 0; i < 8; ++i)
        o[i] = (xv[i] - mean) * rsq * gamma[l * 8 + i] + beta[l * 8 + i];
    float4 o0 = { o[0], o[1], o[2], o[3] }, o1 = { o[4], o[5], o[6], o[7] };
    *(float4*)&h[row * 512 + l * 8] = o0;
    *(float4*)&h[row * 512 + l * 8 + 4] = o1;
    ushort8 ob;
#pragma unroll
    for (int i = 0; i < 8; ++i) ob[i] = f2bf(o[i]);
    *(ushort8*)&hb[row * 512 + l * 8] = ob;
}

// ---------------------------------------------------------------------------
// out = LN(h + f0 + f1) with f0/f1 bf16 partials; writes fp32 out only.
// ---------------------------------------------------------------------------
__global__ __launch_bounds__(64) void add_ln_ffn(
    const float* __restrict__ h, const u16* __restrict__ f0,
    const u16* __restrict__ f1,
    const float* __restrict__ gamma, const float* __restrict__ beta,
    float* __restrict__ outf)
{
    ll row = blockIdx.x;
    int l = threadIdx.x;
    const float* ph = h + row * 512;
    float4 h0 = *(const float4*)&ph[l * 8], h1 = *(const float4*)&ph[l * 8 + 4];
    ushort8 a = *(const ushort8*)&f0[row * 512 + l * 8];
    ushort8 bv = *(const ushort8*)&f1[row * 512 + l * 8];
    float xa[8] = { h0.x, h0.y, h0.z, h0.w, h1.x, h1.y, h1.z, h1.w };
    float xv[8];
#pragma unroll
    for (int i = 0; i < 8; ++i) xv[i] = xa[i] + bf2f(a[i]) + bf2f(bv[i]);
    float s = 0.f, ss = 0.f;
#pragma unroll
    for (int i = 0; i < 8; ++i) { s += xv[i]; ss += xv[i] * xv[i]; }
#pragma unroll
    for (int off = 32; off; off >>= 1) {
        s += __shfl_xor(s, off);
        ss += __shfl_xor(ss, off);
    }
    float mean = s * (1.f / 512.f);
    float var = ss * (1.f / 512.f) - mean * mean;
    float rsq = rsqrtf(var + 1e-14f);
    float o[8];
#pragma unroll
    for (int i = 0; i < 8; ++i)
        o[i] = (xv[i] - mean) * rsq * gamma[l * 8 + i] + beta[l * 8 + i];
    float4 o0 = { o[0], o[1], o[2], o[3] }, o1 = { o[4], o[5], o[6], o[7] };
    *(float4*)&outf[row * 512 + l * 8] = o0;
    *(float4*)&outf[row * 512 + l * 8 + 4] = o1;
}

// ---------------------------------------------------------------------------
extern "C" void kernel_launch(void* const* d_in, const int* in_sizes, int n_in,
                              void* d_out, int out_size, void* d_ws, size_t ws_size,
                              hipStream_t stream)
{
    const float* x      = (const float*)d_in[0];
    const float* Wq     = (const float*)d_in[1];
    const float* bq     = (const float*)d_in[2];
    const float* Wk     = (const float*)d_in[3];
    const float* bk     = (const float*)d_in[4];
    const float* Wv     = (const float*)d_in[5];
    const float* bv     = (const float*)d_in[6];
    const float* gamma1 = (const float*)d_in[7];
    const float* beta1  = (const float*)d_in[8];
    const float* gamma2 = (const float*)d_in[9];
    const float* beta2  = (const float*)d_in[10];
    const float* W1     = (const float*)d_in[11];
    const float* b1     = (const float*)d_in[12];
    const float* W2     = (const float*)d_in[13];
    const float* b2     = (const float*)d_in[14];

    const int B = 4, S = 2048, D = 512, F = 2048;
    const int BS = B * S;  // 8192

    char* w = (char*)d_ws;
    auto alloc = [&](size_t bytes) {
        char* p = w;
        w += (bytes + 255) & ~(size_t)255;
        return p;
    };
    u16* wqkvT = (u16*)alloc((size_t)3 * D * D * 2);   // [1536][512]
    float* bqkv = (float*)alloc((size_t)3 * D * 4);
    u16* w1T = (u16*)alloc((size_t)F * D * 2);         // [F][D]
    u16* w2T = (u16*)alloc((size_t)D * F * 2);         // [D][F]
    u16* xb  = (u16*)alloc((size_t)BS * D * 2);        // reused as hb
    u16* qkvb = (u16*)alloc((size_t)BS * 3 * D * 2);   // [BS][1536]
    u16* attnb = (u16*)alloc((size_t)B * S * S * 2);   // 32MB P~; reused as f1
    u16* vT  = (u16*)alloc((size_t)B * D * S * 2);     // [B][512][2048] 8MB
    u16* ybp = (u16*)alloc((size_t)2 * BS * D * 2);    // y~ partials; reused f0/f1p
    float* h = (float*)alloc((size_t)BS * D * 4);      // 16MB
    float* lpart = (float*)alloc((size_t)16 * BS * 4); // 512KB row-sum partials

    u16* hb = xb;
    u16* y0b = ybp, * y1b = ybp + (size_t)BS * D;
    u16* f0 = y0b, * f1p = y1b;                        // overlay after y dead
    u16* f1 = attnb;                                   // [BS,F] bf16 (P~ dead)

    // 1. effective QKV weights (stacked/transposed) + bias concat
    reduce_qkv_w<<<dim3(D * D / 256), 256, 0, stream>>>(Wq, Wk, Wv, wqkvT);
    concat_bias<<<dim3(6), 256, 0, stream>>>(bq, bk, bv, bqkv);
    // 2-3. W1T [F][D], W2T [D][F]
    transpose_k<true><<<dim3(D / 64, F / 64, 1), 256, 0, stream>>>(
        W1, w1T, F, D, 0, 0);
    transpose_k<true><<<dim3(F / 64, D / 64, 1), 256, 0, stream>>>(
        W2, w2T, D, F, 0, 0);
    // 4. x -> bf16
    cvt_f32_bf16<<<dim3(BS * D / 8 / 256), 256, 0, stream>>>(x, xb, (ll)BS * D);
    // 5. fused qkv = x @ Wqkv^T + bqkv -> [BS][1536]
    gemm3<1><<<dim3(BS / 128, 3 * D / 128, 1), 256, 0, stream>>>(
        xb, wqkvT, qkvb, bqkv, nullptr, D, D, 3 * D, D, 1, 1.f, 0, 0, 0, 0);
    // 6. P~ = exp(q @ k^T / 8) -> bf16 + row-sum partials lpart[16][8192]
    gemm3<2><<<dim3(S / 128, S / 128, B), 256, 0, stream>>>(
        qkvb, qkvb + D, attnb, nullptr, lpart, 3 * D, 3 * D, S, D, 1, 0.125f,
        (ll)S * 3 * D, (ll)S * 3 * D, (ll)S * S, 0);
    // 7. vT[b][e][t] = v[b][t][e]
    transpose_k<false><<<dim3(S / 64, D / 64, B), 256, 0, stream>>>(
        qkvb + 2 * D, vT, 3 * D, S, (ll)S * 3 * D, (ll)D * S);
    // 8. y~ = P~ @ v, split-K=2 -> bf16 unnormalized partials y0b,y1b
    gemm3<1><<<dim3(S / 128, D / 128, B * 2), 256, 0, stream>>>(
        attnb, vT, y0b, nullptr, nullptr, S, S, D, S / 2, 2, 1.f,
        (ll)S * S, (ll)D * S, (ll)S * D, (ll)BS * D);
    // 9. h = LN(x + (y0+y1)/l) -> fp32 + bf16
    add_ln_attn<<<dim3(BS), 64, 0, stream>>>(x, y0b, y1b, lpart,
                                             gamma1, beta1, h, hb);
    // 10. f1 = h @ W1 + b1 (bf16; overlays attnb)
    gemm3<1><<<dim3(BS / 128, F / 128, 1), 256, 0, stream>>>(
        hb, w1T, f1, b1, nullptr, D, D, F, D, 1, 1.f, 0, 0, 0, 0);
    // 11. f2 = f1 @ W2 + b2, split-K=2 -> bf16 partials f0, f1p (y dead)
    gemm3<1><<<dim3(BS / 128, D / 128, 2), 256, 0, stream>>>(
        f1, w2T, f0, b2, nullptr, F, F, D, F / 2, 2, 1.f, 0, 0, 0, (ll)BS * D);
    // 12. out = LN(h + f0 + f1p)
    add_ln_ffn<<<dim3(BS), 64, 0, stream>>>(h, f0, f1p, gamma2, beta2,
                                            (float*)d_out);
}

// Round 9
// 176.375 us; speedup vs baseline: 1.7006x; 1.0372x over previous
//
#include <hip/hip_runtime.h>

typedef unsigned short u16;
typedef u16 ushort8 __attribute__((ext_vector_type(8)));
typedef __bf16 bf16x8 __attribute__((ext_vector_type(8)));
typedef float f32x4 __attribute__((ext_vector_type(4)));
typedef long long ll;

__device__ __forceinline__ u16 f2bf(float f) {
    unsigned u = __builtin_bit_cast(unsigned, f);
    u += 0x7FFFu + ((u >> 16) & 1u);
    return (u16)(u >> 16);
}
__device__ __forceinline__ float bf2f(u16 h) {
    return __builtin_bit_cast(float, (unsigned)h << 16);
}

// async global->LDS, 16B per lane, wave-uniform LDS base + lane*16
#define GLOAD16(dst, src) \
    __builtin_amdgcn_global_load_lds( \
        (const __attribute__((address_space(1))) void*)(src), \
        (__attribute__((address_space(3))) void*)(dst), 16, 0, 0)

// ---------------------------------------------------------------------------
// prep_all: one launch for all independent preprocessing.
//   blocks [0,1024):    WqkvT[e][d] (stacked q|k|v effective weights, bf16)
//   blocks [1024,1280): W1T [F][D]
//   blocks [1280,1536): W2T [D][F]
//   blocks [1536,3584): x -> bf16
//   blocks [3584,3590): bqkv concat
// ---------------------------------------------------------------------------
__global__ __launch_bounds__(256) void prep_all(
    const float* __restrict__ Wq, const float* __restrict__ Wk,
    const float* __restrict__ Wv, u16* __restrict__ WqkvT,
    const float* __restrict__ W1, u16* __restrict__ w1T,
    const float* __restrict__ W2, u16* __restrict__ w2T,
    const float* __restrict__ x, u16* __restrict__ xb,
    const float* __restrict__ bq, const float* __restrict__ bk,
    const float* __restrict__ bv, float* __restrict__ bqkv)
{
    __shared__ u16 tile[64][65];
    const int bid = blockIdx.x;
    const int tid = threadIdx.x;

    if (bid < 1024) {
        int idx = bid * 256 + tid;              // 0 .. 512*512-1
        int e = idx & 511, d = idx >> 9;
        float sq = 0.f, sk = 0.f, sv = 0.f;
#pragma unroll
        for (int h = 0; h < 8; ++h) {
            ll off = (ll)(h * 512 + d) * 512 + e;
            sq += Wq[off]; sk += Wk[off]; sv += Wv[off];
        }
        int o = e * 512 + d;
        WqkvT[o] = f2bf(sq);
        WqkvT[512 * 512 + o] = f2bf(sk);
        WqkvT[1024 * 512 + o] = f2bf(sv);
    } else if (bid < 1536) {
        // transpose W1 [512][2048] -> w1T [2048][512]   (id grid 8 x 32)
        // or        W2 [2048][512] -> w2T [512][2048]   (id grid 32 x 8)
        const bool isW1 = bid < 1280;
        const int id = isW1 ? (bid - 1024) : (bid - 1280);
        const int bx = isW1 ? (id & 7) : (id & 31);
        const int by = isW1 ? (id >> 3) : (id >> 5);
        const float* in = isW1 ? W1 : W2;
        u16* out = isW1 ? w1T : w2T;
        const int ldin = isW1 ? 2048 : 512;
        const int ldout = isW1 ? 512 : 2048;
        const int r0 = bx * 64, c0 = by * 64;
#pragma unroll
        for (int i = 0; i < 16; ++i) {
            int lin = tid + i * 256;
            int rr = lin >> 6, cc = lin & 63;
            tile[rr][cc] = f2bf(in[(ll)(r0 + rr) * ldin + (c0 + cc)]);
        }
        __syncthreads();
#pragma unroll
        for (int i = 0; i < 16; ++i) {
            int lin = tid + i * 256;
            int rr = lin >> 6, cc = lin & 63;
            out[(ll)(c0 + rr) * ldout + (r0 + cc)] = tile[cc][rr];
        }
    } else if (bid < 3584) {
        ll i = ((ll)(bid - 1536) * 256 + tid) * 8;
        float4 a = *(const float4*)&x[i];
        float4 b = *(const float4*)&x[i + 4];
        ushort8 o;
        o[0] = f2bf(a.x); o[1] = f2bf(a.y); o[2] = f2bf(a.z); o[3] = f2bf(a.w);
        o[4] = f2bf(b.x); o[5] = f2bf(b.y); o[6] = f2bf(b.z); o[7] = f2bf(b.w);
        *(ushort8*)&xb[i] = o;
    } else {
        int i = (bid - 3584) * 256 + tid;  // 0..1535
        float v = (i < 512) ? bq[i] : (i < 1024 ? bk[i - 512] : bv[i - 1024]);
        bqkv[i] = v;
    }
}

// ---------------------------------------------------------------------------
// bf16 MFMA GEMM, m97 structure: 128x128 tile, BK=64, global_load_lds w=16,
// XOR-swizzled LDS.
// EPI: 1 = bf16 out
//      2 = bf16(exp(alpha*v)) + per-block row-sum partials to lpart
//      3 = qkv split: cols <1024 -> C (ld 1536); cols >=1024 -> vTout[b][d][t]
// grid: (M/128, N/128, batch*nsplit); 256 thr = 4 waves (2x2 of 64x64).
// ---------------------------------------------------------------------------
template<int EPI>
__global__ __launch_bounds__(256) void gemm3(
    const u16* __restrict__ A, const u16* __restrict__ Bt,
    void* __restrict__ C, const float* __restrict__ bias,
    float* __restrict__ lpart, u16* __restrict__ vTout,
    int lda, int ldb, int ldc, int Kslice, int nsplit, float alpha,
    ll strideA, ll strideB, ll strideC, ll sliceStrideC)
{
    __shared__ __attribute__((aligned(16))) u16 smA[128 * 64];  // 16 KB
    __shared__ __attribute__((aligned(16))) u16 smB[128 * 64];  // 16 KB

    const int z = blockIdx.z;
    const int b = z / nsplit, s = z - b * nsplit;
    A  += (ll)b * strideA + (ll)s * Kslice;
    Bt += (ll)b * strideB + (ll)s * Kslice;
    const ll cbase = (ll)b * strideC + (ll)s * sliceStrideC;

    const int bm = blockIdx.x * 128, bn = blockIdx.y * 128;
    const int t = threadIdx.x, w = t >> 6, l = t & 63;
    const int wm = (w >> 1) * 64, wn = (w & 1) * 64;
    const int lr = l & 15, lg = l >> 4;

    // staging: wave w owns rows [w*32, w*32+32); 4 gloads of 8 rows each.
    // lane l -> LDS row offset l>>3, chunk l&7; global chunk (l&7)^(l>>3)
    const int srow = l >> 3;
    const int schunk = (l & 7) ^ srow;
    const u16* ga = A + (ll)(bm + w * 32 + srow) * lda + schunk * 8;
    const u16* gb = Bt + (ll)(bn + w * 32 + srow) * ldb + schunk * 8;

    f32x4 acc[4][4] = {};

    for (int k0 = 0; k0 < Kslice; k0 += 64) {
#pragma unroll
        for (int g = 0; g < 4; ++g) {
            GLOAD16(&smA[(w * 32 + g * 8) * 64], ga + (ll)(g * 8) * lda);
            GLOAD16(&smB[(w * 32 + g * 8) * 64], gb + (ll)(g * 8) * ldb);
        }
        ga += 64; gb += 64;
        __syncthreads();   // drains vmcnt -> tiles ready

#pragma unroll
        for (int ks = 0; ks < 2; ++ks) {
            bf16x8 af[4], bfr[4];
#pragma unroll
            for (int i = 0; i < 4; ++i) {
                int ra = wm + i * 16 + lr;
                af[i] = *(const bf16x8*)&smA[ra * 64 + ((((ks << 2) | lg)) ^ (ra & 7)) * 8];
            }
#pragma unroll
            for (int i = 0; i < 4; ++i) {
                int rb = wn + i * 16 + lr;
                bfr[i] = *(const bf16x8*)&smB[rb * 64 + ((((ks << 2) | lg)) ^ (rb & 7)) * 8];
            }
#pragma unroll
            for (int mi = 0; mi < 4; ++mi)
#pragma unroll
                for (int ni = 0; ni < 4; ++ni)
                    acc[mi][ni] = __builtin_amdgcn_mfma_f32_16x16x32_bf16(
                        af[mi], bfr[ni], acc[mi][ni], 0, 0, 0);
        }
        __syncthreads();
    }

    // epilogue: C/D mapping col = lane&15, row = (lane>>4)*4 + j
    const bool addb = (bias != nullptr) && (s == 0);
    float rs[4][4] = {};   // per-(mi,j) partial row sums (EPI==2 only)
#pragma unroll
    for (int ni = 0; ni < 4; ++ni) {
        const int col = bn + wn + ni * 16 + lr;
        const float bv = addb ? bias[col] : 0.f;
        const bool vsec = (EPI == 3) && (col >= 1024);   // uniform per ni
#pragma unroll
        for (int mi = 0; mi < 4; ++mi) {
#pragma unroll
            for (int j = 0; j < 4; ++j) {
                const int row = bm + wm + mi * 16 + lg * 4 + j;
                float v = acc[mi][ni][j] * alpha + bv;
                if (EPI == 2) { v = __expf(v); rs[mi][j] += v; }
                if (vsec) {
                    const int bb = row >> 11, tt = row & 2047;
                    vTout[((ll)bb * 512 + (col - 1024)) * 2048 + tt] = f2bf(v);
                } else {
                    ((u16*)C)[cbase + (ll)row * ldc + col] = f2bf(v);
                }
            }
        }
    }

    if (EPI == 2) {
        // reduce rs across 16 lr lanes, combine col-half waves via LDS,
        // write one 128-row partial-sum vector per block.
        float* lsum = (float*)smA;   // 256 floats (K-loop ended with barrier)
#pragma unroll
        for (int mi = 0; mi < 4; ++mi)
#pragma unroll
            for (int j = 0; j < 4; ++j) {
                float s2 = rs[mi][j];
                s2 += __shfl_xor(s2, 1);
                s2 += __shfl_xor(s2, 2);
                s2 += __shfl_xor(s2, 4);
                s2 += __shfl_xor(s2, 8);
                if (lr == 0)
                    lsum[(w & 1) * 128 + wm + mi * 16 + lg * 4 + j] = s2;
            }
        __syncthreads();
        if (t < 128)
            lpart[(ll)blockIdx.y * 8192 + (ll)b * 2048 + bm + t] =
                lsum[t] + lsum[128 + t];
    }
}

// ---------------------------------------------------------------------------
// hb = bf16( LN(x + (y0+y1)/l) ), l = sum of 16 lpart partials; y0/y1 bf16.
// rows of 512, 1 wave/row.
// ---------------------------------------------------------------------------
__global__ __launch_bounds__(64) void add_ln_attn(
    const float* __restrict__ x, const u16* __restrict__ y0,
    const u16* __restrict__ y1, const float* __restrict__ lpart,
    const float* __restrict__ gamma, const float* __restrict__ beta,
    u16* __restrict__ hb)
{
    ll row = blockIdx.x;
    int l = threadIdx.x;
    float lsum = 0.f;
#pragma unroll
    for (int j = 0; j < 16; ++j) lsum += lpart[j * 8192 + row];  // uniform
    float inv = 1.f / lsum;
    const float* px = x + row * 512;
    float4 x0 = *(const float4*)&px[l * 8], x1 = *(const float4*)&px[l * 8 + 4];
    ushort8 a = *(const ushort8*)&y0[row * 512 + l * 8];
    ushort8 bv = *(const ushort8*)&y1[row * 512 + l * 8];
    float xa[8] = { x0.x, x0.y, x0.z, x0.w, x1.x, x1.y, x1.z, x1.w };
    float xv[8];
#pragma unroll
    for (int i = 0; i < 8; ++i)
        xv[i] = xa[i] + (bf2f(a[i]) + bf2f(bv[i])) * inv;
    float s = 0.f, ss = 0.f;
#pragma unroll
    for (int i = 0; i < 8; ++i) { s += xv[i]; ss += xv[i] * xv[i]; }
#pragma unroll
    for (int off = 32; off; off >>= 1) {
        s += __shfl_xor(s, off);
        ss += __shfl_xor(ss, off);
    }
    float mean = s * (1.f / 512.f);
    float var = ss * (1.f / 512.f) - mean * mean;
    float rsq = rsqrtf(var + 1e-14f);
    ushort8 ob;
#pragma unroll
    for (int i = 0; i < 8; ++i)
        ob[i] = f2bf((xv[i] - mean) * rsq * gamma[l * 8 + i] + beta[l * 8 + i]);
    *(ushort8*)&hb[row * 512 + l * 8] = ob;
}

// ---------------------------------------------------------------------------
// out = LN(hb + f0 + f1) with hb/f0/f1 bf16; writes fp32 out.
// ---------------------------------------------------------------------------
__global__ __launch_bounds__(64) void add_ln_ffn(
    const u16* __restrict__ hb, const u16* __restrict__ f0,
    const u16* __restrict__ f1,
    const float* __restrict__ gamma, const float* __restrict__ beta,
    float* __restrict__ outf)
{
    ll row = blockIdx.x;
    int l = threadIdx.x;
    ushort8 hh = *(const ushort8*)&hb[row * 512 + l * 8];
    ushort8 a = *(const ushort8*)&f0[row * 512 + l * 8];
    ushort8 bv = *(const ushort8*)&f1[row * 512 + l * 8];
    float xv[8];
#pragma unroll
    for (int i = 0; i < 8; ++i)
        xv[i] = bf2f(hh[i]) + bf2f(a[i]) + bf2f(bv[i]);
    float s = 0.f, ss = 0.f;
#pragma unroll
    for (int i = 0; i < 8; ++i) { s += xv[i]; ss += xv[i] * xv[i]; }
#pragma unroll
    for (int off = 32; off; off >>= 1) {
        s += __shfl_xor(s, off);
        ss += __shfl_xor(ss, off);
    }
    float mean = s * (1.f / 512.f);
    float var = ss * (1.f / 512.f) - mean * mean;
    float rsq = rsqrtf(var + 1e-14f);
    float o[8];
#pragma unroll
    for (int i = 0; i < 8; ++i)
        o[i] = (xv[i] - mean) * rsq * gamma[l * 8 + i] + beta[l * 8 + i];
    float4 o0 = { o[0], o[1], o[2], o[3] }, o1 = { o[4], o[5], o[6], o[7] };
    *(float4*)&outf[row * 512 + l * 8] = o0;
    *(float4*)&outf[row * 512 + l * 8 + 4] = o1;
}

// ---------------------------------------------------------------------------
extern "C" void kernel_launch(void* const* d_in, const int* in_sizes, int n_in,
                              void* d_out, int out_size, void* d_ws, size_t ws_size,
                              hipStream_t stream)
{
    const float* x      = (const float*)d_in[0];
    const float* Wq     = (const float*)d_in[1];
    const float* bq     = (const float*)d_in[2];
    const float* Wk     = (const float*)d_in[3];
    const float* bk     = (const float*)d_in[4];
    const float* Wv     = (const float*)d_in[5];
    const float* bv     = (const float*)d_in[6];
    const float* gamma1 = (const float*)d_in[7];
    const float* beta1  = (const float*)d_in[8];
    const float* gamma2 = (const float*)d_in[9];
    const float* beta2  = (const float*)d_in[10];
    const float* W1     = (const float*)d_in[11];
    const float* b1     = (const float*)d_in[12];
    const float* W2     = (const float*)d_in[13];
    const float* b2     = (const float*)d_in[14];

    const int B = 4, S = 2048, D = 512, F = 2048;
    const int BS = B * S;  // 8192

    char* w = (char*)d_ws;
    auto alloc = [&](size_t bytes) {
        char* p = w;
        w += (bytes + 255) & ~(size_t)255;
        return p;
    };
    u16* wqkvT = (u16*)alloc((size_t)3 * D * D * 2);   // [1536][512]
    float* bqkv = (float*)alloc((size_t)3 * D * 4);
    u16* w1T = (u16*)alloc((size_t)F * D * 2);         // [F][D]
    u16* w2T = (u16*)alloc((size_t)D * F * 2);         // [D][F]
    u16* xb  = (u16*)alloc((size_t)BS * D * 2);        // reused as hb
    u16* qkvb = (u16*)alloc((size_t)BS * 3 * D * 2);   // [BS][1536] (v third unused)
    u16* attnb = (u16*)alloc((size_t)B * S * S * 2);   // 32MB P~; reused as f1
    u16* vT  = (u16*)alloc((size_t)B * D * S * 2);     // [B][512][2048] 8MB
    u16* ybp = (u16*)alloc((size_t)2 * BS * D * 2);    // y~ partials; reused f0/f1p
    float* lpart = (float*)alloc((size_t)16 * BS * 4); // 512KB row-sum partials

    u16* hb = xb;
    u16* y0b = ybp, * y1b = ybp + (size_t)BS * D;
    u16* f0 = y0b, * f1p = y1b;                        // overlay after y dead
    u16* f1 = attnb;                                   // [BS,F] bf16 (P~ dead)

    // 1. all preprocessing in one launch
    prep_all<<<dim3(3590), 256, 0, stream>>>(
        Wq, Wk, Wv, wqkvT, W1, w1T, W2, w2T, x, xb, bq, bk, bv, bqkv);
    // 2. qkv = x @ Wqkv^T + bqkv -> qkvb (q,k) + vT (v transposed)
    gemm3<3><<<dim3(BS / 128, 3 * D / 128, 1), 256, 0, stream>>>(
        xb, wqkvT, qkvb, bqkv, nullptr, vT, D, D, 3 * D, D, 1, 1.f, 0, 0, 0, 0);
    // 3. P~ = exp(q @ k^T / 8) -> bf16 + row-sum partials lpart[16][8192]
    gemm3<2><<<dim3(S / 128, S / 128, B), 256, 0, stream>>>(
        qkvb, qkvb + D, attnb, nullptr, lpart, nullptr, 3 * D, 3 * D, S, D, 1,
        0.125f, (ll)S * 3 * D, (ll)S * 3 * D, (ll)S * S, 0);
    // 4. y~ = P~ @ v, split-K=2 -> bf16 unnormalized partials y0b,y1b
    gemm3<1><<<dim3(S / 128, D / 128, B * 2), 256, 0, stream>>>(
        attnb, vT, y0b, nullptr, nullptr, nullptr, S, S, D, S / 2, 2, 1.f,
        (ll)S * S, (ll)D * S, (ll)S * D, (ll)BS * D);
    // 5. hb = bf16(LN(x + (y0+y1)/l))
    add_ln_attn<<<dim3(BS), 64, 0, stream>>>(x, y0b, y1b, lpart,
                                             gamma1, beta1, hb);
    // 6. f1 = h @ W1 + b1 (bf16; overlays attnb)
    gemm3<1><<<dim3(BS / 128, F / 128, 1), 256, 0, stream>>>(
        hb, w1T, f1, b1, nullptr, nullptr, D, D, F, D, 1, 1.f, 0, 0, 0, 0);
    // 7. f2 = f1 @ W2 + b2, split-K=2 -> bf16 partials f0, f1p (y dead)
    gemm3<1><<<dim3(BS / 128, D / 128, 2), 256, 0, stream>>>(
        f1, w2T, f0, b2, nullptr, nullptr, F, F, D, F / 2, 2, 1.f, 0, 0, 0,
        (ll)BS * D);
    // 8. out = LN(hb + f0 + f1p)
    add_ln_ffn<<<dim3(BS), 64, 0, stream>>>(hb, f0, f1p, gamma2, beta2,
                                            (float*)d_out);
}

// Round 10
// 173.808 us; speedup vs baseline: 1.7257x; 1.0148x over previous
//
#include <hip/hip_runtime.h>

typedef unsigned short u16;
typedef u16 ushort8 __attribute__((ext_vector_type(8)));
typedef __bf16 bf16x8 __attribute__((ext_vector_type(8)));
typedef float f32x4 __attribute__((ext_vector_type(4)));
typedef long long ll;

__device__ __forceinline__ u16 f2bf(float f) {
    unsigned u = __builtin_bit_cast(unsigned, f);
    u += 0x7FFFu + ((u >> 16) & 1u);
    return (u16)(u >> 16);
}
__device__ __forceinline__ float bf2f(u16 h) {
    return __builtin_bit_cast(float, (unsigned)h << 16);
}

// async global->LDS, 16B per lane, wave-uniform LDS base + lane*16
#define GLOAD16(dst, src) \
    __builtin_amdgcn_global_load_lds( \
        (const __attribute__((address_space(1))) void*)(src), \
        (__attribute__((address_space(3))) void*)(dst), 16, 0, 0)

// ---------------------------------------------------------------------------
// prep_all: one launch for all independent preprocessing (round-9 proven).
// ---------------------------------------------------------------------------
__global__ __launch_bounds__(256) void prep_all(
    const float* __restrict__ Wq, const float* __restrict__ Wk,
    const float* __restrict__ Wv, u16* __restrict__ WqkvT,
    const float* __restrict__ W1, u16* __restrict__ w1T,
    const float* __restrict__ W2, u16* __restrict__ w2T,
    const float* __restrict__ x, u16* __restrict__ xb,
    const float* __restrict__ bq, const float* __restrict__ bk,
    const float* __restrict__ bv, float* __restrict__ bqkv)
{
    __shared__ u16 tile[64][65];
    const int bid = blockIdx.x;
    const int tid = threadIdx.x;

    if (bid < 1024) {
        int idx = bid * 256 + tid;              // 0 .. 512*512-1
        int e = idx & 511, d = idx >> 9;
        float sq = 0.f, sk = 0.f, sv = 0.f;
#pragma unroll
        for (int h = 0; h < 8; ++h) {
            ll off = (ll)(h * 512 + d) * 512 + e;
            sq += Wq[off]; sk += Wk[off]; sv += Wv[off];
        }
        int o = e * 512 + d;
        WqkvT[o] = f2bf(sq);
        WqkvT[512 * 512 + o] = f2bf(sk);
        WqkvT[1024 * 512 + o] = f2bf(sv);
    } else if (bid < 1536) {
        const bool isW1 = bid < 1280;
        const int id = isW1 ? (bid - 1024) : (bid - 1280);
        const int bx = isW1 ? (id & 7) : (id & 31);
        const int by = isW1 ? (id >> 3) : (id >> 5);
        const float* in = isW1 ? W1 : W2;
        u16* out = isW1 ? w1T : w2T;
        const int ldin = isW1 ? 2048 : 512;
        const int ldout = isW1 ? 512 : 2048;
        const int r0 = bx * 64, c0 = by * 64;
#pragma unroll
        for (int i = 0; i < 16; ++i) {
            int lin = tid + i * 256;
            int rr = lin >> 6, cc = lin & 63;
            tile[rr][cc] = f2bf(in[(ll)(r0 + rr) * ldin + (c0 + cc)]);
        }
        __syncthreads();
#pragma unroll
        for (int i = 0; i < 16; ++i) {
            int lin = tid + i * 256;
            int rr = lin >> 6, cc = lin & 63;
            out[(ll)(c0 + rr) * ldout + (r0 + cc)] = tile[cc][rr];
        }
    } else if (bid < 3584) {
        ll i = ((ll)(bid - 1536) * 256 + tid) * 8;
        float4 a = *(const float4*)&x[i];
        float4 b = *(const float4*)&x[i + 4];
        ushort8 o;
        o[0] = f2bf(a.x); o[1] = f2bf(a.y); o[2] = f2bf(a.z); o[3] = f2bf(a.w);
        o[4] = f2bf(b.x); o[5] = f2bf(b.y); o[6] = f2bf(b.z); o[7] = f2bf(b.w);
        *(ushort8*)&xb[i] = o;
    } else {
        int i = (bid - 3584) * 256 + tid;  // 0..1535
        float v = (i < 512) ? bq[i] : (i < 1024 ? bk[i - 512] : bv[i - 1024]);
        bqkv[i] = v;
    }
}

// ---------------------------------------------------------------------------
// gemm3: 128x128 tile, BK=64, global_load_lds w=16, XOR-swizzled (proven).
// EPI: 1 = bf16 out
//      3 = qkv split: cols <1024 -> C (ld 1536); cols >=1024 -> vTout[b][d][t]
// ---------------------------------------------------------------------------
template<int EPI>
__global__ __launch_bounds__(256) void gemm3(
    const u16* __restrict__ A, const u16* __restrict__ Bt,
    void* __restrict__ C, const float* __restrict__ bias,
    u16* __restrict__ vTout,
    int lda, int ldb, int ldc, int Kslice, int nsplit, float alpha,
    ll strideA, ll strideB, ll strideC, ll sliceStrideC)
{
    __shared__ __attribute__((aligned(16))) u16 smA[128 * 64];  // 16 KB
    __shared__ __attribute__((aligned(16))) u16 smB[128 * 64];  // 16 KB

    const int z = blockIdx.z;
    const int b = z / nsplit, s = z - b * nsplit;
    A  += (ll)b * strideA + (ll)s * Kslice;
    Bt += (ll)b * strideB + (ll)s * Kslice;
    const ll cbase = (ll)b * strideC + (ll)s * sliceStrideC;

    const int bm = blockIdx.x * 128, bn = blockIdx.y * 128;
    const int t = threadIdx.x, w = t >> 6, l = t & 63;
    const int wm = (w >> 1) * 64, wn = (w & 1) * 64;
    const int lr = l & 15, lg = l >> 4;

    const int srow = l >> 3;
    const int schunk = (l & 7) ^ srow;
    const u16* ga = A + (ll)(bm + w * 32 + srow) * lda + schunk * 8;
    const u16* gb = Bt + (ll)(bn + w * 32 + srow) * ldb + schunk * 8;

    f32x4 acc[4][4] = {};

    for (int k0 = 0; k0 < Kslice; k0 += 64) {
#pragma unroll
        for (int g = 0; g < 4; ++g) {
            GLOAD16(&smA[(w * 32 + g * 8) * 64], ga + (ll)(g * 8) * lda);
            GLOAD16(&smB[(w * 32 + g * 8) * 64], gb + (ll)(g * 8) * ldb);
        }
        ga += 64; gb += 64;
        __syncthreads();

#pragma unroll
        for (int ks = 0; ks < 2; ++ks) {
            bf16x8 af[4], bfr[4];
#pragma unroll
            for (int i = 0; i < 4; ++i) {
                int ra = wm + i * 16 + lr;
                af[i] = *(const bf16x8*)&smA[ra * 64 + ((((ks << 2) | lg)) ^ (ra & 7)) * 8];
            }
#pragma unroll
            for (int i = 0; i < 4; ++i) {
                int rb = wn + i * 16 + lr;
                bfr[i] = *(const bf16x8*)&smB[rb * 64 + ((((ks << 2) | lg)) ^ (rb & 7)) * 8];
            }
#pragma unroll
            for (int mi = 0; mi < 4; ++mi)
#pragma unroll
                for (int ni = 0; ni < 4; ++ni)
                    acc[mi][ni] = __builtin_amdgcn_mfma_f32_16x16x32_bf16(
                        af[mi], bfr[ni], acc[mi][ni], 0, 0, 0);
        }
        __syncthreads();
    }

    const bool addb = (bias != nullptr) && (s == 0);
#pragma unroll
    for (int ni = 0; ni < 4; ++ni) {
        const int col = bn + wn + ni * 16 + lr;
        const float bv = addb ? bias[col] : 0.f;
        const bool vsec = (EPI == 3) && (col >= 1024);
#pragma unroll
        for (int mi = 0; mi < 4; ++mi) {
#pragma unroll
            for (int j = 0; j < 4; ++j) {
                const int row = bm + wm + mi * 16 + lg * 4 + j;
                float v = acc[mi][ni][j] * alpha + bv;
                if (vsec) {
                    const int bb = row >> 11, tt = row & 2047;
                    vTout[((ll)bb * 512 + (col - 1024)) * 2048 + tt] = f2bf(v);
                } else {
                    ((u16*)C)[cbase + (ll)row * ldc + col] = f2bf(v);
                }
            }
        }
    }
}

// ---------------------------------------------------------------------------
// gemm256: 256x256 tile, BK=64, 8 waves (2Mx4N), double-buffered LDS with
// prefetch-before-compute (T3 minimum 2-phase). Same XOR swizzle as gemm3.
// EPI: 1 = bf16 out (+bias); 2 = bf16(exp(alpha*v)) + lpart[blockIdx.y][row]
// grid: (M/256, N/256, batch); 512 threads.
// ---------------------------------------------------------------------------
template<int EPI>
__global__ __launch_bounds__(512, 2) void gemm256(
    const u16* __restrict__ A, const u16* __restrict__ Bt,
    void* __restrict__ C, const float* __restrict__ bias,
    float* __restrict__ lpart,
    int lda, int ldb, int ldc, int K, float alpha,
    ll strideA, ll strideB, ll strideC)
{
    __shared__ __attribute__((aligned(16))) u16 sm[2][2][256 * 64];  // 128 KB

    const int b = blockIdx.z;
    A  += (ll)b * strideA;
    Bt += (ll)b * strideB;
    const ll cbase = (ll)b * strideC;

    const int bm = blockIdx.x * 256, bn = blockIdx.y * 256;
    const int t = threadIdx.x, w = t >> 6, l = t & 63;
    const int wm = (w >> 2) * 128, wn = (w & 3) * 64;
    const int lr = l & 15, lg = l >> 4;

    // staging: gload g covers rows g*64 + w*8 + (l>>3), chunk l&7 in LDS;
    // global chunk pre-swizzled by ^(row&7) = ^(l>>3).
    const int srow = l >> 3;
    const int schunk = (l & 7) ^ srow;
    const u16* ga = A + (ll)(bm + w * 8 + srow) * lda + schunk * 8;
    const u16* gb = Bt + (ll)(bn + w * 8 + srow) * ldb + schunk * 8;

    f32x4 acc[8][4] = {};

    const int nt = K / 64;
    // prologue: stage K-tile 0 into buf 0
#pragma unroll
    for (int g = 0; g < 4; ++g) {
        GLOAD16(&sm[0][0][(g * 64 + w * 8) * 64], ga + (ll)(g * 64) * lda);
        GLOAD16(&sm[0][1][(g * 64 + w * 8) * 64], gb + (ll)(g * 64) * ldb);
    }
    __syncthreads();   // drains vmcnt -> buf0 ready

    int cur = 0;
    for (int kt = 0; kt < nt; ++kt) {
        // issue next-tile stage FIRST (flies under compute)
        if (kt + 1 < nt) {
            const u16* a = ga + (ll)(kt + 1) * 64;
            const u16* bb = gb + (ll)(kt + 1) * 64;
#pragma unroll
            for (int g = 0; g < 4; ++g) {
                GLOAD16(&sm[cur ^ 1][0][(g * 64 + w * 8) * 64], a + (ll)(g * 64) * lda);
                GLOAD16(&sm[cur ^ 1][1][(g * 64 + w * 8) * 64], bb + (ll)(g * 64) * ldb);
            }
        }
        // compute current tile
#pragma unroll
        for (int ks = 0; ks < 2; ++ks) {
            bf16x8 bfr[4];
#pragma unroll
            for (int ni = 0; ni < 4; ++ni) {
                int rb = wn + ni * 16 + lr;
                bfr[ni] = *(const bf16x8*)&sm[cur][1][rb * 64 + ((((ks << 2) | lg)) ^ (rb & 7)) * 8];
            }
#pragma unroll
            for (int mi = 0; mi < 8; ++mi) {
                int ra = wm + mi * 16 + lr;
                bf16x8 af = *(const bf16x8*)&sm[cur][0][ra * 64 + ((((ks << 2) | lg)) ^ (ra & 7)) * 8];
#pragma unroll
                for (int ni = 0; ni < 4; ++ni)
                    acc[mi][ni] = __builtin_amdgcn_mfma_f32_16x16x32_bf16(
                        af, bfr[ni], acc[mi][ni], 0, 0, 0);
            }
        }
        __syncthreads();   // drains prefetch vmcnt + all reads of buf[cur]
        cur ^= 1;
    }

    // epilogue: C/D mapping col = lane&15, row = (lane>>4)*4 + j
    const bool addb = (bias != nullptr);
    float rs[8][4] = {};
#pragma unroll
    for (int ni = 0; ni < 4; ++ni) {
        const int col = bn + wn + ni * 16 + lr;
        const float bv = addb ? bias[col] : 0.f;
#pragma unroll
        for (int mi = 0; mi < 8; ++mi) {
#pragma unroll
            for (int j = 0; j < 4; ++j) {
                const int row = bm + wm + mi * 16 + lg * 4 + j;
                float v = acc[mi][ni][j] * alpha + bv;
                if (EPI == 2) { v = __expf(v); rs[mi][j] += v; }
                ((u16*)C)[cbase + (ll)row * ldc + col] = f2bf(v);
            }
        }
    }

    if (EPI == 2) {
        __syncthreads();   // sm reads done (epilogue has no sm use yet)
        float* lsum = (float*)&sm[0][0][0];   // [4 wn][256 rows]
#pragma unroll
        for (int mi = 0; mi < 8; ++mi)
#pragma unroll
            for (int j = 0; j < 4; ++j) {
                float s2 = rs[mi][j];
                s2 += __shfl_xor(s2, 1);
                s2 += __shfl_xor(s2, 2);
                s2 += __shfl_xor(s2, 4);
                s2 += __shfl_xor(s2, 8);
                if (lr == 0)
                    lsum[(w & 3) * 256 + wm + mi * 16 + lg * 4 + j] = s2;
            }
        __syncthreads();
        if (t < 256)
            lpart[(ll)blockIdx.y * 8192 + (ll)b * 2048 + bm + t] =
                lsum[t] + lsum[256 + t] + lsum[512 + t] + lsum[768 + t];
    }
}

// ---------------------------------------------------------------------------
// hb = bf16( LN(x + (y0+y1)/l) ), l = sum of 8 lpart partials; y0/y1 bf16.
// ---------------------------------------------------------------------------
__global__ __launch_bounds__(64) void add_ln_attn(
    const float* __restrict__ x, const u16* __restrict__ y0,
    const u16* __restrict__ y1, const float* __restrict__ lpart,
    const float* __restrict__ gamma, const float* __restrict__ beta,
    u16* __restrict__ hb)
{
    ll row = blockIdx.x;
    int l = threadIdx.x;
    float lsum = 0.f;
#pragma unroll
    for (int j = 0; j < 8; ++j) lsum += lpart[j * 8192 + row];  // uniform
    float inv = 1.f / lsum;
    const float* px = x + row * 512;
    float4 x0 = *(const float4*)&px[l * 8], x1 = *(const float4*)&px[l * 8 + 4];
    ushort8 a = *(const ushort8*)&y0[row * 512 + l * 8];
    ushort8 bv = *(const ushort8*)&y1[row * 512 + l * 8];
    float xa[8] = { x0.x, x0.y, x0.z, x0.w, x1.x, x1.y, x1.z, x1.w };
    float xv[8];
#pragma unroll
    for (int i = 0; i < 8; ++i)
        xv[i] = xa[i] + (bf2f(a[i]) + bf2f(bv[i])) * inv;
    float s = 0.f, ss = 0.f;
#pragma unroll
    for (int i = 0; i < 8; ++i) { s += xv[i]; ss += xv[i] * xv[i]; }
#pragma unroll
    for (int off = 32; off; off >>= 1) {
        s += __shfl_xor(s, off);
        ss += __shfl_xor(ss, off);
    }
    float mean = s * (1.f / 512.f);
    float var = ss * (1.f / 512.f) - mean * mean;
    float rsq = rsqrtf(var + 1e-14f);
    ushort8 ob;
#pragma unroll
    for (int i = 0; i < 8; ++i)
        ob[i] = f2bf((xv[i] - mean) * rsq * gamma[l * 8 + i] + beta[l * 8 + i]);
    *(ushort8*)&hb[row * 512 + l * 8] = ob;
}

// ---------------------------------------------------------------------------
// out = LN(hb + f0 + f1) with hb/f0/f1 bf16; writes fp32 out.
// ---------------------------------------------------------------------------
__global__ __launch_bounds__(64) void add_ln_ffn(
    const u16* __restrict__ hb, const u16* __restrict__ f0,
    const u16* __restrict__ f1,
    const float* __restrict__ gamma, const float* __restrict__ beta,
    float* __restrict__ outf)
{
    ll row = blockIdx.x;
    int l = threadIdx.x;
    ushort8 hh = *(const ushort8*)&hb[row * 512 + l * 8];
    ushort8 a = *(const ushort8*)&f0[row * 512 + l * 8];
    ushort8 bv = *(const ushort8*)&f1[row * 512 + l * 8];
    float xv[8];
#pragma unroll
    for (int i = 0; i < 8; ++i)
        xv[i] = bf2f(hh[i]) + bf2f(a[i]) + bf2f(bv[i]);
    float s = 0.f, ss = 0.f;
#pragma unroll
    for (int i = 0; i < 8; ++i) { s += xv[i]; ss += xv[i] * xv[i]; }
#pragma unroll
    for (int off = 32; off; off >>= 1) {
        s += __shfl_xor(s, off);
        ss += __shfl_xor(ss, off);
    }
    float mean = s * (1.f / 512.f);
    float var = ss * (1.f / 512.f) - mean * mean;
    float rsq = rsqrtf(var + 1e-14f);
    float o[8];
#pragma unroll
    for (int i = 0; i < 8; ++i)
        o[i] = (xv[i] - mean) * rsq * gamma[l * 8 + i] + beta[l * 8 + i];
    float4 o0 = { o[0], o[1], o[2], o[3] }, o1 = { o[4], o[5], o[6], o[7] };
    *(float4*)&outf[row * 512 + l * 8] = o0;
    *(float4*)&outf[row * 512 + l * 8 + 4] = o1;
}

// ---------------------------------------------------------------------------
extern "C" void kernel_launch(void* const* d_in, const int* in_sizes, int n_in,
                              void* d_out, int out_size, void* d_ws, size_t ws_size,
                              hipStream_t stream)
{
    const float* x      = (const float*)d_in[0];
    const float* Wq     = (const float*)d_in[1];
    const float* bq     = (const float*)d_in[2];
    const float* Wk     = (const float*)d_in[3];
    const float* bk     = (const float*)d_in[4];
    const float* Wv     = (const float*)d_in[5];
    const float* bv     = (const float*)d_in[6];
    const float* gamma1 = (const float*)d_in[7];
    const float* beta1  = (const float*)d_in[8];
    const float* gamma2 = (const float*)d_in[9];
    const float* beta2  = (const float*)d_in[10];
    const float* W1     = (const float*)d_in[11];
    const float* b1     = (const float*)d_in[12];
    const float* W2     = (const float*)d_in[13];
    const float* b2     = (const float*)d_in[14];

    const int B = 4, S = 2048, D = 512, F = 2048;
    const int BS = B * S;  // 8192

    char* w = (char*)d_ws;
    auto alloc = [&](size_t bytes) {
        char* p = w;
        w += (bytes + 255) & ~(size_t)255;
        return p;
    };
    u16* wqkvT = (u16*)alloc((size_t)3 * D * D * 2);   // [1536][512]
    float* bqkv = (float*)alloc((size_t)3 * D * 4);
    u16* w1T = (u16*)alloc((size_t)F * D * 2);         // [F][D]
    u16* w2T = (u16*)alloc((size_t)D * F * 2);         // [D][F]
    u16* xb  = (u16*)alloc((size_t)BS * D * 2);        // reused as hb
    u16* qkvb = (u16*)alloc((size_t)BS * 3 * D * 2);   // [BS][1536]
    u16* attnb = (u16*)alloc((size_t)B * S * S * 2);   // 32MB P~; reused as f1
    u16* vT  = (u16*)alloc((size_t)B * D * S * 2);     // [B][512][2048] 8MB
    u16* ybp = (u16*)alloc((size_t)2 * BS * D * 2);    // y~ partials; reused f0/f1p
    float* lpart = (float*)alloc((size_t)8 * BS * 4);  // 256KB row-sum partials

    u16* hb = xb;
    u16* y0b = ybp, * y1b = ybp + (size_t)BS * D;
    u16* f0 = y0b, * f1p = y1b;                        // overlay after y dead
    u16* f1 = attnb;                                   // [BS,F] bf16 (P~ dead)

    // 1. all preprocessing in one launch
    prep_all<<<dim3(3590), 256, 0, stream>>>(
        Wq, Wk, Wv, wqkvT, W1, w1T, W2, w2T, x, xb, bq, bk, bv, bqkv);
    // 2. qkv = x @ Wqkv^T + bqkv -> qkvb (q,k) + vT (v transposed)
    gemm3<3><<<dim3(BS / 128, 3 * D / 128, 1), 256, 0, stream>>>(
        xb, wqkvT, qkvb, bqkv, vT, D, D, 3 * D, D, 1, 1.f, 0, 0, 0, 0);
    // 3. P~ = exp(q @ k^T / 8) -> bf16 + row-sum partials lpart[8][8192]
    gemm256<2><<<dim3(S / 256, S / 256, B), 512, 0, stream>>>(
        qkvb, qkvb + D, attnb, nullptr, lpart, 3 * D, 3 * D, S, D, 0.125f,
        (ll)S * 3 * D, (ll)S * 3 * D, (ll)S * S);
    // 4. y~ = P~ @ v, split-K=2 -> bf16 unnormalized partials y0b,y1b
    gemm3<1><<<dim3(S / 128, D / 128, B * 2), 256, 0, stream>>>(
        attnb, vT, y0b, nullptr, nullptr, S, S, D, S / 2, 2, 1.f,
        (ll)S * S, (ll)D * S, (ll)S * D, (ll)BS * D);
    // 5. hb = bf16(LN(x + (y0+y1)/l))
    add_ln_attn<<<dim3(BS), 64, 0, stream>>>(x, y0b, y1b, lpart,
                                             gamma1, beta1, hb);
    // 6. f1 = h @ W1 + b1 (bf16; overlays attnb)
    gemm256<1><<<dim3(BS / 256, F / 256, 1), 512, 0, stream>>>(
        hb, w1T, f1, b1, nullptr, D, D, F, D, 1.f, 0, 0, 0);
    // 7. f2 = f1 @ W2 + b2, split-K=2 -> bf16 partials f0, f1p (y dead)
    gemm3<1><<<dim3(BS / 128, D / 128, 2), 256, 0, stream>>>(
        f1, w2T, f0, b2, nullptr, F, F, D, F / 2, 2, 1.f, 0, 0, 0,
        (ll)BS * D);
    // 8. out = LN(hb + f0 + f1p)
    add_ln_ffn<<<dim3(BS), 64, 0, stream>>>(hb, f0, f1p, gamma2, beta2,
                                            (float*)d_out);
}